// Round 1
// baseline (955.251 us; speedup 1.0000x reference)
//
#include <hip/hip_runtime.h>

// Decoder block, MI355X. Math note: the reference's triu/swap/softmax/triu
// masking reduces attention to:
//   denom(q) = q + sum_{k>=q} exp(scores[q,k])
//   attn[q]  = ( sum_{k<q} v[k] + exp(scores[q,q])*v[q] ) / denom(q)
// so PV is a prefix sum over V; only upper-triangular row sums of exp(QK^T/sqrt(D))
// are needed. All GEMMs run in bf16 MFMA (threshold 0.155 allows it).

typedef unsigned short ushort_t;
typedef unsigned int   uint32;
typedef __attribute__((ext_vector_type(8))) short    short8;
typedef __attribute__((ext_vector_type(8))) ushort_t ushort8;
typedef __attribute__((ext_vector_type(4))) float    f32x4;

#define BDIM   2
#define SEQ    2048
#define DMODEL 2048
#define NHEAD  16
#define DHEAD  128
#define DFFN   8192
#define MROWS  (BDIM*SEQ)   // 4096

#define GPTR(p) (const __attribute__((address_space(1))) void*)((const void*)(p))
#define SPTR(p) (__attribute__((address_space(3))) void*)((void*)(p))

__device__ __forceinline__ float bf2f(ushort_t u) {
  union { uint32 i; float f; } c; c.i = ((uint32)u) << 16; return c.f;
}
__device__ __forceinline__ ushort_t f2bf(float f) {
  union { float f; uint32 i; } c; c.f = f;
  uint32 u = c.i;
  return (ushort_t)((u + 0x7fffu + ((u >> 16) & 1u)) >> 16);
}

// ---------------- weight transpose fp32[K][N] -> bf16[N][K] ----------------
__global__ __launch_bounds__(256) void transpose_f32_bf16_kern(
    const float* __restrict__ W, ushort_t* __restrict__ Wt, int K, int N)
{
  __shared__ float tile[32][33];
  const int nb = blockIdx.x * 32, kb = blockIdx.y * 32;
  const int tx = threadIdx.x & 31, ty = threadIdx.x >> 5;   // ty: 0..7
#pragma unroll
  for (int j = 0; j < 32; j += 8)
    tile[ty + j][tx] = W[(size_t)(kb + ty + j) * N + nb + tx];
  __syncthreads();
#pragma unroll
  for (int j = 0; j < 32; j += 8)
    Wt[(size_t)(nb + ty + j) * K + kb + tx] = f2bf(tile[tx][ty + j]);
}

// ---------------- LayerNorm fp32 -> bf16, one block per row ----------------
__global__ __launch_bounds__(256) void ln_kern(
    const float* __restrict__ X, const float* __restrict__ G,
    const float* __restrict__ Bb, ushort_t* __restrict__ Out)
{
  const int row = blockIdx.x, tid = threadIdx.x;
  const float* xr = X + (size_t)row * DMODEL;
  float4 v0 = ((const float4*)xr)[tid * 2];
  float4 v1 = ((const float4*)xr)[tid * 2 + 1];
  float s  = v0.x + v0.y + v0.z + v0.w + v1.x + v1.y + v1.z + v1.w;
  float ss = v0.x*v0.x + v0.y*v0.y + v0.z*v0.z + v0.w*v0.w
           + v1.x*v1.x + v1.y*v1.y + v1.z*v1.z + v1.w*v1.w;
#pragma unroll
  for (int off = 32; off > 0; off >>= 1) {
    s  += __shfl_down(s, off);
    ss += __shfl_down(ss, off);
  }
  __shared__ float rs[4], rss[4];
  __shared__ float sh_mu, sh_rst;
  const int wv = tid >> 6;
  if ((tid & 63) == 0) { rs[wv] = s; rss[wv] = ss; }
  __syncthreads();
  if (tid == 0) {
    float S1 = rs[0] + rs[1] + rs[2] + rs[3];
    float S2 = rss[0] + rss[1] + rss[2] + rss[3];
    float mu = S1 * (1.f / DMODEL);
    float var = S2 * (1.f / DMODEL) - mu * mu;
    sh_mu = mu;
    sh_rst = rsqrtf(var + 1e-5f);
  }
  __syncthreads();
  const float mu = sh_mu, rst = sh_rst;
  float4 g0 = ((const float4*)G)[tid * 2];
  float4 g1 = ((const float4*)G)[tid * 2 + 1];
  float4 b0 = ((const float4*)Bb)[tid * 2];
  float4 b1 = ((const float4*)Bb)[tid * 2 + 1];
  ushort8 o;
  o[0] = f2bf((v0.x - mu) * rst * g0.x + b0.x);
  o[1] = f2bf((v0.y - mu) * rst * g0.y + b0.y);
  o[2] = f2bf((v0.z - mu) * rst * g0.z + b0.z);
  o[3] = f2bf((v0.w - mu) * rst * g0.w + b0.w);
  o[4] = f2bf((v1.x - mu) * rst * g1.x + b1.x);
  o[5] = f2bf((v1.y - mu) * rst * g1.y + b1.y);
  o[6] = f2bf((v1.z - mu) * rst * g1.z + b1.z);
  o[7] = f2bf((v1.w - mu) * rst * g1.w + b1.w);
  *(ushort8*)(Out + (size_t)row * DMODEL + tid * 8) = o;
}

// ---------------- GEMM: C[M,N] = A[M,K](bf16) * Bt[N,K]^T(bf16) + bias -----
// m97 structure: 128x128 tile, 4 waves of 64x64, BK=32, global_load_lds(16B).
template<int OUT_BF16, int RELU, int RESID>
__global__ __launch_bounds__(256) void gemm_bt_kern(
    const ushort_t* __restrict__ A, const ushort_t* __restrict__ Bt,
    const float* __restrict__ bias, const float* __restrict__ resid,
    void* __restrict__ Cout, int M, int N, int K)
{
  __shared__ ushort_t Asm[128 * 32];
  __shared__ ushort_t Bsm[128 * 32];
  const int tid = threadIdx.x;
  const int n0 = blockIdx.x * 128, m0 = blockIdx.y * 128;
  const int l  = tid & 63, w = tid >> 6;
  const int lr = l & 15, lg = l >> 4;
  const int wm = (w >> 1) * 64, wn = (w & 1) * 64;

  // staging: thread t stages 16B chunk t of each 4KB half-tile (linear LDS)
  const int r0 = tid >> 2;            // 0..63
  const int kc = (tid & 3) * 8;
  const ushort_t* Ag0 = A  + (size_t)(m0 + r0)      * K + kc;
  const ushort_t* Ag1 = A  + (size_t)(m0 + 64 + r0) * K + kc;
  const ushort_t* Bg0 = Bt + (size_t)(n0 + r0)      * K + kc;
  const ushort_t* Bg1 = Bt + (size_t)(n0 + 64 + r0) * K + kc;
  ushort_t* As0 = Asm + tid * 8;
  ushort_t* As1 = Asm + 2048 + tid * 8;
  ushort_t* Bs0 = Bsm + tid * 8;
  ushort_t* Bs1 = Bsm + 2048 + tid * 8;

  f32x4 acc[4][4] = {};

  for (int kt = 0; kt < K; kt += 32) {
    __syncthreads();
    __builtin_amdgcn_global_load_lds(GPTR(Ag0 + kt), SPTR(As0), 16, 0, 0);
    __builtin_amdgcn_global_load_lds(GPTR(Ag1 + kt), SPTR(As1), 16, 0, 0);
    __builtin_amdgcn_global_load_lds(GPTR(Bg0 + kt), SPTR(Bs0), 16, 0, 0);
    __builtin_amdgcn_global_load_lds(GPTR(Bg1 + kt), SPTR(Bs1), 16, 0, 0);
    __syncthreads();

    short8 af[4], bfr[4];
#pragma unroll
    for (int i = 0; i < 4; ++i)
      af[i] = *(const short8*)(Asm + (wm + i * 16 + lr) * 32 + lg * 8);
#pragma unroll
    for (int i = 0; i < 4; ++i)
      bfr[i] = *(const short8*)(Bsm + (wn + i * 16 + lr) * 32 + lg * 8);
#pragma unroll
    for (int mi = 0; mi < 4; ++mi)
#pragma unroll
      for (int ni = 0; ni < 4; ++ni)
        acc[mi][ni] = __builtin_amdgcn_mfma_f32_16x16x32_bf16(
            af[mi], bfr[ni], acc[mi][ni], 0, 0, 0);
  }

#pragma unroll
  for (int mi = 0; mi < 4; ++mi) {
#pragma unroll
    for (int ni = 0; ni < 4; ++ni) {
      const int gn = n0 + wn + ni * 16 + lr;
      const float bvv = bias[gn];
#pragma unroll
      for (int j = 0; j < 4; ++j) {
        const int gm = m0 + wm + mi * 16 + lg * 4 + j;
        float v = acc[mi][ni][j] + bvv;
        if (RESID) v += resid[(size_t)gm * N + gn];
        if (RELU) v = fmaxf(v, 0.f);
        if (OUT_BF16) ((ushort_t*)Cout)[(size_t)gm * N + gn] = f2bf(v);
        else          ((float*)Cout)[(size_t)gm * N + gn] = v;
      }
    }
  }
}

// ---------------- attention stats: E[q]=sum_{k>=q} exp(s), DG[q]=exp(s_qq) --
// one wave per (bh, 16 q-rows); MFMA 16x16 score tiles, frags straight from
// global (contiguous 16B per lane).
__global__ __launch_bounds__(64) void attn_stats_kern(
    const ushort_t* __restrict__ Q, const ushort_t* __restrict__ Kb,
    float* __restrict__ E, float* __restrict__ DG)
{
  const int qt = blockIdx.x;        // 0..127
  const int bh = blockIdx.y;        // 0..31
  const int b = bh >> 4, h = bh & 15;
  const int l = threadIdx.x;
  const int lr = l & 15, lg = l >> 4;
  const int qbase = qt * 16;

  const size_t qoff = (size_t)(b * SEQ + qbase + lr) * DMODEL + h * DHEAD + lg * 8;
  short8 af[4];
#pragma unroll
  for (int c = 0; c < 4; ++c) af[c] = *(const short8*)(Q + qoff + c * 32);

  f32x4 sume = {0.f, 0.f, 0.f, 0.f};
  f32x4 dge  = {0.f, 0.f, 0.f, 0.f};
  const float scale = 0.0220970869120796f;   // 1/sqrt(2048)

  for (int kt = qt; kt < SEQ / 16; ++kt) {
    const size_t koff = (size_t)(b * SEQ + kt * 16 + lr) * DMODEL + h * DHEAD + lg * 8;
    short8 b0 = *(const short8*)(Kb + koff);
    short8 b1 = *(const short8*)(Kb + koff + 32);
    short8 b2 = *(const short8*)(Kb + koff + 64);
    short8 b3 = *(const short8*)(Kb + koff + 96);
    f32x4 sc = {0.f, 0.f, 0.f, 0.f};
    sc = __builtin_amdgcn_mfma_f32_16x16x32_bf16(af[0], b0, sc, 0, 0, 0);
    sc = __builtin_amdgcn_mfma_f32_16x16x32_bf16(af[1], b1, sc, 0, 0, 0);
    sc = __builtin_amdgcn_mfma_f32_16x16x32_bf16(af[2], b2, sc, 0, 0, 0);
    sc = __builtin_amdgcn_mfma_f32_16x16x32_bf16(af[3], b3, sc, 0, 0, 0);
    const int ki = kt * 16 + lr;
#pragma unroll
    for (int j = 0; j < 4; ++j) {
      const int qi = qbase + lg * 4 + j;
      if (ki >= qi) {
        float e = __expf(sc[j] * scale);
        sume[j] += e;
        if (ki == qi) dge[j] += e;
      }
    }
  }
#pragma unroll
  for (int j = 0; j < 4; ++j) {
#pragma unroll
    for (int off = 1; off < 16; off <<= 1) {
      sume[j] += __shfl_xor(sume[j], off);
      dge[j]  += __shfl_xor(dge[j], off);
    }
  }
  if (lr == 0) {
#pragma unroll
    for (int j = 0; j < 4; ++j) {
      E[(size_t)bh * SEQ + qbase + lg * 4 + j]  = sume[j];
      DG[(size_t)bh * SEQ + qbase + lg * 4 + j] = dge[j];
    }
  }
}

// ---------------- V chunk sums (64-row chunks) -----------------------------
__global__ __launch_bounds__(128) void vchunk_kern(
    const ushort_t* __restrict__ V, float* __restrict__ CS)
{
  const int c = blockIdx.x, bh = blockIdx.y;
  const int b = bh >> 4, h = bh & 15;
  const int dh = threadIdx.x;
  const ushort_t* vp = V + (size_t)(b * SEQ + c * 64) * DMODEL + h * DHEAD + dh;
  float s = 0.f;
  for (int i = 0; i < 64; ++i) s += bf2f(vp[(size_t)i * DMODEL]);
  CS[((size_t)bh * 32 + c) * 128 + dh] = s;
}

// ---------------- combine: attn = (prefixV + diag*v)/denom -> bf16 ---------
__global__ __launch_bounds__(128) void attn_combine_kern(
    const ushort_t* __restrict__ V, const float* __restrict__ CS,
    const float* __restrict__ E, const float* __restrict__ DG,
    ushort_t* __restrict__ Attn)
{
  const int c = blockIdx.x, bh = blockIdx.y;
  const int b = bh >> 4, h = bh & 15;
  const int dh = threadIdx.x;
  float prefix = 0.f;
  for (int cc = 0; cc < c; ++cc) prefix += CS[((size_t)bh * 32 + cc) * 128 + dh];
  const ushort_t* vp = V + (size_t)(b * SEQ + c * 64) * DMODEL + h * DHEAD + dh;
  ushort_t* ap = Attn + (size_t)(b * SEQ + c * 64) * DMODEL + h * DHEAD + dh;
  const int qb = c * 64;
  for (int i = 0; i < 64; ++i) {
    const int qq = qb + i;
    const float denom = (float)qq + E[(size_t)bh * SEQ + qq];
    const float de = DG[(size_t)bh * SEQ + qq];
    const float vv = bf2f(vp[(size_t)i * DMODEL]);
    ap[(size_t)i * DMODEL] = f2bf((prefix + de * vv) / denom);
    prefix += vv;
  }
}

// ---------------------------------------------------------------------------
extern "C" void kernel_launch(void* const* d_in, const int* in_sizes, int n_in,
                              void* d_out, int out_size, void* d_ws, size_t ws_size,
                              hipStream_t stream)
{
  const float* x    = (const float*)d_in[0];
  const float* wq   = (const float*)d_in[1];
  const float* bq   = (const float*)d_in[2];
  const float* wk   = (const float*)d_in[3];
  const float* bk   = (const float*)d_in[4];
  const float* wv   = (const float*)d_in[5];
  const float* bv   = (const float*)d_in[6];
  const float* wo   = (const float*)d_in[7];
  const float* bo   = (const float*)d_in[8];
  const float* ln1g = (const float*)d_in[9];
  const float* ln1b = (const float*)d_in[10];
  const float* w1   = (const float*)d_in[11];
  const float* b1   = (const float*)d_in[12];
  const float* w2   = (const float*)d_in[13];
  const float* b2   = (const float*)d_in[14];
  const float* ln2g = (const float*)d_in[15];
  const float* ln2b = (const float*)d_in[16];
  float* out = (float*)d_out;

  // ws layout (bytes). F1 pool reuses regions dead by the time FF1 runs.
  char* ws = (char*)d_ws;
  ushort_t* W1T  = (ushort_t*)(ws + 0);            // 33554432
  ushort_t* W2T  = (ushort_t*)(ws + 33554432);     // 33554432
  ushort_t* WOT  = (ushort_t*)(ws + 67108864);     //  8388608
  float*    X2   = (float*)   (ws + 75497472);     // 33554432
  ushort_t* Hb   = (ushort_t*)(ws + 109051904);    // 16777216 (h / attn / h2)
  ushort_t* F1   = (ushort_t*)(ws + 125829120);    // 67108864 (overlaps below)
  ushort_t* WQT  = (ushort_t*)(ws + 125829120);    //  8388608
  ushort_t* WKT  = (ushort_t*)(ws + 134217728);    //  8388608
  ushort_t* WVT  = (ushort_t*)(ws + 142606336);    //  8388608
  ushort_t* Qb   = (ushort_t*)(ws + 150994944);    // 16777216
  ushort_t* Kbuf = (ushort_t*)(ws + 167772160);    // 16777216
  ushort_t* Vb   = (ushort_t*)(ws + 184549376);    // 16777216
  float*    Eb   = (float*)   (ws + 201326592);    //   262144
  float*    DGb  = (float*)   (ws + 201588736);    //   262144
  float*    CSb  = (float*)   (ws + 201850880);    //   524288  (end ~193 MiB)

  // 1. weight transposes (fp32 -> bf16 [N][K])
  transpose_f32_bf16_kern<<<dim3(64, 64),  256, 0, stream>>>(wq, WQT, 2048, 2048);
  transpose_f32_bf16_kern<<<dim3(64, 64),  256, 0, stream>>>(wk, WKT, 2048, 2048);
  transpose_f32_bf16_kern<<<dim3(64, 64),  256, 0, stream>>>(wv, WVT, 2048, 2048);
  transpose_f32_bf16_kern<<<dim3(64, 64),  256, 0, stream>>>(wo, WOT, 2048, 2048);
  transpose_f32_bf16_kern<<<dim3(256, 64), 256, 0, stream>>>(w1, W1T, 2048, 8192);
  transpose_f32_bf16_kern<<<dim3(64, 256), 256, 0, stream>>>(w2, W2T, 8192, 2048);

  // 2. LN1: x -> h (bf16)
  ln_kern<<<MROWS, 256, 0, stream>>>(x, ln1g, ln1b, Hb);

  // 3-5. QKV projections
  gemm_bt_kern<1, 0, 0><<<dim3(16, 32), 256, 0, stream>>>(Hb, WQT, bq, nullptr, Qb,   MROWS, DMODEL, DMODEL);
  gemm_bt_kern<1, 0, 0><<<dim3(16, 32), 256, 0, stream>>>(Hb, WKT, bk, nullptr, Kbuf, MROWS, DMODEL, DMODEL);
  gemm_bt_kern<1, 0, 0><<<dim3(16, 32), 256, 0, stream>>>(Hb, WVT, bv, nullptr, Vb,   MROWS, DMODEL, DMODEL);

  // 6. attention stats (upper-tri exp row sums + diagonal)
  attn_stats_kern<<<dim3(128, 32), 64, 0, stream>>>(Qb, Kbuf, Eb, DGb);

  // 7. V prefix machinery + combine -> attn (into Hb, h is dead)
  vchunk_kern<<<dim3(32, 32), 128, 0, stream>>>(Vb, CSb);
  attn_combine_kern<<<dim3(32, 32), 128, 0, stream>>>(Vb, CSb, Eb, DGb, Hb);

  // 8. O projection + residual(x) -> X2 (fp32)
  gemm_bt_kern<0, 0, 1><<<dim3(16, 32), 256, 0, stream>>>(Hb, WOT, bo, x, X2, MROWS, DMODEL, DMODEL);

  // 9. LN2: X2 -> h2 (bf16, reuse Hb)
  ln_kern<<<MROWS, 256, 0, stream>>>(X2, ln2g, ln2b, Hb);

  // 10. FF1 + ReLU -> F1 (bf16)
  gemm_bt_kern<1, 1, 0><<<dim3(64, 32), 256, 0, stream>>>(Hb, W1T, b1, nullptr, F1, MROWS, DFFN, DMODEL);

  // 11. FF2 + residual(X2) -> out (fp32)
  gemm_bt_kern<0, 0, 1><<<dim3(16, 32), 256, 0, stream>>>(F1, W2T, b2, X2, out, MROWS, DMODEL, DFFN);
}

// Round 3
// 785.542 us; speedup vs baseline: 1.2160x; 1.2160x over previous
//
#include <hip/hip_runtime.h>

// Decoder block, MI355X. Math note: the reference's triu/swap/softmax/triu
// masking reduces attention to:
//   denom(q) = q + sum_{k>=q} exp(scores[q,k])
//   attn[q]  = ( sum_{k<q} v[k] + exp(scores[q,q])*v[q] ) / denom(q)
// so PV is a prefix sum over V; only upper-triangular row sums of exp(QK^T/sqrt(D))
// are needed. All GEMMs run in bf16 MFMA (threshold 0.155 allows it).

typedef unsigned short ushort_t;
typedef unsigned int   uint32;
typedef __attribute__((ext_vector_type(8))) short    short8;
typedef __attribute__((ext_vector_type(8))) ushort_t ushort8;
typedef __attribute__((ext_vector_type(4))) float    f32x4;

#define BDIM   2
#define SEQ    2048
#define DMODEL 2048
#define NHEAD  16
#define DHEAD  128
#define DFFN   8192
#define MROWS  (BDIM*SEQ)   // 4096

#define GPTR(p) (const __attribute__((address_space(1))) void*)((const void*)(p))
#define SPTR(p) (__attribute__((address_space(3))) void*)((void*)(p))

__device__ __forceinline__ float bf2f(ushort_t u) {
  union { uint32 i; float f; } c; c.i = ((uint32)u) << 16; return c.f;
}
__device__ __forceinline__ ushort_t f2bf(float f) {
  union { float f; uint32 i; } c; c.f = f;
  uint32 u = c.i;
  return (ushort_t)((u + 0x7fffu + ((u >> 16) & 1u)) >> 16);
}

// ---------------- weight transpose fp32[K][N] -> bf16[N][K] ----------------
__global__ __launch_bounds__(256) void transpose_f32_bf16_kern(
    const float* __restrict__ W, ushort_t* __restrict__ Wt, int K, int N)
{
  __shared__ float tile[32][33];
  const int nb = blockIdx.x * 32, kb = blockIdx.y * 32;
  const int tx = threadIdx.x & 31, ty = threadIdx.x >> 5;   // ty: 0..7
#pragma unroll
  for (int j = 0; j < 32; j += 8)
    tile[ty + j][tx] = W[(size_t)(kb + ty + j) * N + nb + tx];
  __syncthreads();
#pragma unroll
  for (int j = 0; j < 32; j += 8)
    Wt[(size_t)(nb + ty + j) * K + kb + tx] = f2bf(tile[tx][ty + j]);
}

// ---------------- LayerNorm fp32 -> bf16, one block per row ----------------
__global__ __launch_bounds__(256) void ln_kern(
    const float* __restrict__ X, const float* __restrict__ G,
    const float* __restrict__ Bb, ushort_t* __restrict__ Out)
{
  const int row = blockIdx.x, tid = threadIdx.x;
  const float* xr = X + (size_t)row * DMODEL;
  float4 v0 = ((const float4*)xr)[tid * 2];
  float4 v1 = ((const float4*)xr)[tid * 2 + 1];
  float s  = v0.x + v0.y + v0.z + v0.w + v1.x + v1.y + v1.z + v1.w;
  float ss = v0.x*v0.x + v0.y*v0.y + v0.z*v0.z + v0.w*v0.w
           + v1.x*v1.x + v1.y*v1.y + v1.z*v1.z + v1.w*v1.w;
#pragma unroll
  for (int off = 32; off > 0; off >>= 1) {
    s  += __shfl_down(s, off);
    ss += __shfl_down(ss, off);
  }
  __shared__ float rs[4], rss[4];
  __shared__ float sh_mu, sh_rst;
  const int wv = tid >> 6;
  if ((tid & 63) == 0) { rs[wv] = s; rss[wv] = ss; }
  __syncthreads();
  if (tid == 0) {
    float S1 = rs[0] + rs[1] + rs[2] + rs[3];
    float S2 = rss[0] + rss[1] + rss[2] + rss[3];
    float mu = S1 * (1.f / DMODEL);
    float var = S2 * (1.f / DMODEL) - mu * mu;
    sh_mu = mu;
    sh_rst = rsqrtf(var + 1e-5f);
  }
  __syncthreads();
  const float mu = sh_mu, rst = sh_rst;
  float4 g0 = ((const float4*)G)[tid * 2];
  float4 g1 = ((const float4*)G)[tid * 2 + 1];
  float4 b0 = ((const float4*)Bb)[tid * 2];
  float4 b1 = ((const float4*)Bb)[tid * 2 + 1];
  ushort8 o;
  o[0] = f2bf((v0.x - mu) * rst * g0.x + b0.x);
  o[1] = f2bf((v0.y - mu) * rst * g0.y + b0.y);
  o[2] = f2bf((v0.z - mu) * rst * g0.z + b0.z);
  o[3] = f2bf((v0.w - mu) * rst * g0.w + b0.w);
  o[4] = f2bf((v1.x - mu) * rst * g1.x + b1.x);
  o[5] = f2bf((v1.y - mu) * rst * g1.y + b1.y);
  o[6] = f2bf((v1.z - mu) * rst * g1.z + b1.z);
  o[7] = f2bf((v1.w - mu) * rst * g1.w + b1.w);
  *(ushort8*)(Out + (size_t)row * DMODEL + tid * 8) = o;
}

// ---------------- GEMM: C[M,N] = A[M,K](bf16) * Bt[N,K]^T(bf16) + bias -----
// m97 structure: 128x128 tile, 4 waves of 64x64, BK=32, global_load_lds(16B).
template<int OUT_BF16, int RELU, int RESID>
__global__ __launch_bounds__(256) void gemm_bt_kern(
    const ushort_t* __restrict__ A, const ushort_t* __restrict__ Bt,
    const float* __restrict__ bias, const float* __restrict__ resid,
    void* __restrict__ Cout, int M, int N, int K)
{
  __shared__ ushort_t Asm[128 * 32];
  __shared__ ushort_t Bsm[128 * 32];
  const int tid = threadIdx.x;
  const int n0 = blockIdx.x * 128, m0 = blockIdx.y * 128;
  const int l  = tid & 63, w = tid >> 6;
  const int lr = l & 15, lg = l >> 4;
  const int wm = (w >> 1) * 64, wn = (w & 1) * 64;

  // staging: thread t stages 16B chunk t of each 4KB half-tile (linear LDS)
  const int r0 = tid >> 2;            // 0..63
  const int kc = (tid & 3) * 8;
  const ushort_t* Ag0 = A  + (size_t)(m0 + r0)      * K + kc;
  const ushort_t* Ag1 = A  + (size_t)(m0 + 64 + r0) * K + kc;
  const ushort_t* Bg0 = Bt + (size_t)(n0 + r0)      * K + kc;
  const ushort_t* Bg1 = Bt + (size_t)(n0 + 64 + r0) * K + kc;
  ushort_t* As0 = Asm + tid * 8;
  ushort_t* As1 = Asm + 2048 + tid * 8;
  ushort_t* Bs0 = Bsm + tid * 8;
  ushort_t* Bs1 = Bsm + 2048 + tid * 8;

  f32x4 acc[4][4] = {};

  for (int kt = 0; kt < K; kt += 32) {
    __syncthreads();
    __builtin_amdgcn_global_load_lds(GPTR(Ag0 + kt), SPTR(As0), 16, 0, 0);
    __builtin_amdgcn_global_load_lds(GPTR(Ag1 + kt), SPTR(As1), 16, 0, 0);
    __builtin_amdgcn_global_load_lds(GPTR(Bg0 + kt), SPTR(Bs0), 16, 0, 0);
    __builtin_amdgcn_global_load_lds(GPTR(Bg1 + kt), SPTR(Bs1), 16, 0, 0);
    __syncthreads();

    short8 af[4], bfr[4];
#pragma unroll
    for (int i = 0; i < 4; ++i)
      af[i] = *(const short8*)(Asm + (wm + i * 16 + lr) * 32 + lg * 8);
#pragma unroll
    for (int i = 0; i < 4; ++i)
      bfr[i] = *(const short8*)(Bsm + (wn + i * 16 + lr) * 32 + lg * 8);
#pragma unroll
    for (int mi = 0; mi < 4; ++mi)
#pragma unroll
      for (int ni = 0; ni < 4; ++ni)
        acc[mi][ni] = __builtin_amdgcn_mfma_f32_16x16x32_bf16(
            af[mi], bfr[ni], acc[mi][ni], 0, 0, 0);
  }

#pragma unroll
  for (int mi = 0; mi < 4; ++mi) {
#pragma unroll
    for (int ni = 0; ni < 4; ++ni) {
      const int gn = n0 + wn + ni * 16 + lr;
      const float bvv = bias[gn];
#pragma unroll
      for (int j = 0; j < 4; ++j) {
        const int gm = m0 + wm + mi * 16 + lg * 4 + j;
        float v = acc[mi][ni][j] + bvv;
        if (RESID) v += resid[(size_t)gm * N + gn];
        if (RELU) v = fmaxf(v, 0.f);
        if (OUT_BF16) ((ushort_t*)Cout)[(size_t)gm * N + gn] = f2bf(v);
        else          ((float*)Cout)[(size_t)gm * N + gn] = v;
      }
    }
  }
}

// ---------------- attention stats v2 ---------------------------------------
// E[q] = sum_{k>=q} exp(s[q,k]*scale), DG[q] = exp(s[q,q]*scale).
// 256 threads = 4 waves; block owns 64 q-rows of one (b,h); K staged in LDS
// 64 rows at a time (16 KB) via global_load_lds with chunk-XOR swizzle
// (chunk' = chunk ^ (row&7)) applied on the GLOBAL SOURCE address (LDS dest
// linear) and the same XOR on the ds_read side -> 2-way banks (free).
__global__ __launch_bounds__(256) void attn_stats_kern(
    const ushort_t* __restrict__ Q, const ushort_t* __restrict__ Kb,
    float* __restrict__ E, float* __restrict__ DG)
{
  __shared__ ushort_t Ksm[64 * 128];   // 16 KB
  const int qb = blockIdx.x;           // 0..31 -> q rows [qb*64, qb*64+64)
  const int bh = blockIdx.y;           // 0..31
  const int b = bh >> 4, h = bh & 15;
  const int tid = threadIdx.x;
  const int l = tid & 63, w = tid >> 6;
  const int lr = l & 15, lg = l >> 4;

  const int qrow0 = qb * 64 + w * 16;  // wave's q-subtile

  // Q fragments (A operand), row = lr, loaded once
  const size_t qoff = (size_t)(b * SEQ + qrow0 + lr) * DMODEL + h * DHEAD + lg * 8;
  short8 af[4];
#pragma unroll
  for (int c = 0; c < 4; ++c) af[c] = *(const short8*)(Q + qoff + c * 32);

  // staging source mapping: wave w call c covers LDS rows w*16+c*4+(l>>4),
  // lds chunk cl=l&15; source chunk g = cl ^ (row&7)
  const int srow_b = w * 16 + (l >> 4);           // + c*4
  const ushort_t* Kg = Kb + (size_t)b * SEQ * DMODEL + (size_t)h * DHEAD;
  ushort_t* Sbase = Ksm + w * 2048;               // + c*512 (ushort units)

  f32x4 sume = {0.f, 0.f, 0.f, 0.f};
  f32x4 dge  = {0.f, 0.f, 0.f, 0.f};
  const float scale = 0.0220970869120796f;        // 1/sqrt(2048)
  const int rx = lr & 7;                          // read-side xor key

  for (int kc = qb; kc < 32; ++kc) {
    __syncthreads();
#pragma unroll
    for (int c = 0; c < 4; ++c) {
      const int row = srow_b + c * 4;
      const int g = (l & 15) ^ (row & 7);
      __builtin_amdgcn_global_load_lds(
          GPTR(Kg + (size_t)(kc * 64 + row) * DMODEL + g * 8),
          SPTR(Sbase + c * 512), 16, 0, 0);
    }
    __syncthreads();

    const int ks0 = (kc == qb) ? w : 0;           // skip fully-masked subtiles
    for (int ks = ks0; ks < 4; ++ks) {
      short8 bfr[4];
#pragma unroll
      for (int c = 0; c < 4; ++c)
        bfr[c] = *(const short8*)(Ksm + (ks * 16 + lr) * 128 + ((lg + c * 4) ^ rx) * 8);
      f32x4 sc = {0.f, 0.f, 0.f, 0.f};
      sc = __builtin_amdgcn_mfma_f32_16x16x32_bf16(af[0], bfr[0], sc, 0, 0, 0);
      sc = __builtin_amdgcn_mfma_f32_16x16x32_bf16(af[1], bfr[1], sc, 0, 0, 0);
      sc = __builtin_amdgcn_mfma_f32_16x16x32_bf16(af[2], bfr[2], sc, 0, 0, 0);
      sc = __builtin_amdgcn_mfma_f32_16x16x32_bf16(af[3], bfr[3], sc, 0, 0, 0);
      if (kc == qb && ks == w) {
        // diagonal tile: masked path + diag extraction
        const int ki = kc * 64 + ks * 16 + lr;
#pragma unroll
        for (int j = 0; j < 4; ++j) {
          const int qi = qrow0 + lg * 4 + j;
          if (ki >= qi) {
            float e = __expf(sc[j] * scale);
            sume[j] += e;
            if (ki == qi) dge[j] += e;
          }
        }
      } else {
#pragma unroll
        for (int j = 0; j < 4; ++j)
          sume[j] += __expf(sc[j] * scale);
      }
    }
  }

#pragma unroll
  for (int j = 0; j < 4; ++j) {
#pragma unroll
    for (int off = 1; off < 16; off <<= 1) {
      sume[j] += __shfl_xor(sume[j], off);
      dge[j]  += __shfl_xor(dge[j], off);
    }
  }
  if (lr == 0) {
#pragma unroll
    for (int j = 0; j < 4; ++j) {
      E[(size_t)bh * SEQ + qrow0 + lg * 4 + j]  = sume[j];
      DG[(size_t)bh * SEQ + qrow0 + lg * 4 + j] = dge[j];
    }
  }
}

// ---------------- V chunk sums (64-row chunks) -----------------------------
__global__ __launch_bounds__(128) void vchunk_kern(
    const ushort_t* __restrict__ V, float* __restrict__ CS)
{
  const int c = blockIdx.x, bh = blockIdx.y;
  const int b = bh >> 4, h = bh & 15;
  const int dh = threadIdx.x;
  const ushort_t* vp = V + (size_t)(b * SEQ + c * 64) * DMODEL + h * DHEAD + dh;
  float s = 0.f;
  for (int i = 0; i < 64; ++i) s += bf2f(vp[(size_t)i * DMODEL]);
  CS[((size_t)bh * 32 + c) * 128 + dh] = s;
}

// ---------------- combine: attn = (prefixV + diag*v)/denom -> bf16 ---------
__global__ __launch_bounds__(128) void attn_combine_kern(
    const ushort_t* __restrict__ V, const float* __restrict__ CS,
    const float* __restrict__ E, const float* __restrict__ DG,
    ushort_t* __restrict__ Attn)
{
  const int c = blockIdx.x, bh = blockIdx.y;
  const int b = bh >> 4, h = bh & 15;
  const int dh = threadIdx.x;
  float prefix = 0.f;
  for (int cc = 0; cc < c; ++cc) prefix += CS[((size_t)bh * 32 + cc) * 128 + dh];
  const ushort_t* vp = V + (size_t)(b * SEQ + c * 64) * DMODEL + h * DHEAD + dh;
  ushort_t* ap = Attn + (size_t)(b * SEQ + c * 64) * DMODEL + h * DHEAD + dh;
  const int qb = c * 64;
  for (int i = 0; i < 64; ++i) {
    const int qq = qb + i;
    const float denom = (float)qq + E[(size_t)bh * SEQ + qq];
    const float de = DG[(size_t)bh * SEQ + qq];
    const float vv = bf2f(vp[(size_t)i * DMODEL]);
    ap[(size_t)i * DMODEL] = f2bf((prefix + de * vv) / denom);
    prefix += vv;
  }
}

// ---------------------------------------------------------------------------
extern "C" void kernel_launch(void* const* d_in, const int* in_sizes, int n_in,
                              void* d_out, int out_size, void* d_ws, size_t ws_size,
                              hipStream_t stream)
{
  const float* x    = (const float*)d_in[0];
  const float* wq   = (const float*)d_in[1];
  const float* bq   = (const float*)d_in[2];
  const float* wk   = (const float*)d_in[3];
  const float* bk   = (const float*)d_in[4];
  const float* wv   = (const float*)d_in[5];
  const float* bv   = (const float*)d_in[6];
  const float* wo   = (const float*)d_in[7];
  const float* bo   = (const float*)d_in[8];
  const float* ln1g = (const float*)d_in[9];
  const float* ln1b = (const float*)d_in[10];
  const float* w1   = (const float*)d_in[11];
  const float* b1   = (const float*)d_in[12];
  const float* w2   = (const float*)d_in[13];
  const float* b2   = (const float*)d_in[14];
  const float* ln2g = (const float*)d_in[15];
  const float* ln2b = (const float*)d_in[16];
  float* out = (float*)d_out;

  // ws layout (bytes). F1 pool reuses regions dead by the time FF1 runs.
  char* ws = (char*)d_ws;
  ushort_t* W1T  = (ushort_t*)(ws + 0);            // 33554432
  ushort_t* W2T  = (ushort_t*)(ws + 33554432);     // 33554432
  ushort_t* WOT  = (ushort_t*)(ws + 67108864);     //  8388608
  float*    X2   = (float*)   (ws + 75497472);     // 33554432
  ushort_t* Hb   = (ushort_t*)(ws + 109051904);    // 16777216 (h / attn / h2)
  ushort_t* F1   = (ushort_t*)(ws + 125829120);    // 67108864 (overlaps below)
  ushort_t* WQT  = (ushort_t*)(ws + 125829120);    //  8388608
  ushort_t* WKT  = (ushort_t*)(ws + 134217728);    //  8388608
  ushort_t* WVT  = (ushort_t*)(ws + 142606336);    //  8388608
  ushort_t* Qb   = (ushort_t*)(ws + 150994944);    // 16777216
  ushort_t* Kbuf = (ushort_t*)(ws + 167772160);    // 16777216
  ushort_t* Vb   = (ushort_t*)(ws + 184549376);    // 16777216
  float*    Eb   = (float*)   (ws + 201326592);    //   262144
  float*    DGb  = (float*)   (ws + 201588736);    //   262144
  float*    CSb  = (float*)   (ws + 201850880);    //   524288  (end ~193 MiB)

  // 1. weight transposes (fp32 -> bf16 [N][K])
  transpose_f32_bf16_kern<<<dim3(64, 64),  256, 0, stream>>>(wq, WQT, 2048, 2048);
  transpose_f32_bf16_kern<<<dim3(64, 64),  256, 0, stream>>>(wk, WKT, 2048, 2048);
  transpose_f32_bf16_kern<<<dim3(64, 64),  256, 0, stream>>>(wv, WVT, 2048, 2048);
  transpose_f32_bf16_kern<<<dim3(64, 64),  256, 0, stream>>>(wo, WOT, 2048, 2048);
  transpose_f32_bf16_kern<<<dim3(256, 64), 256, 0, stream>>>(w1, W1T, 2048, 8192);
  transpose_f32_bf16_kern<<<dim3(64, 256), 256, 0, stream>>>(w2, W2T, 8192, 2048);

  // 2. LN1: x -> h (bf16)
  ln_kern<<<MROWS, 256, 0, stream>>>(x, ln1g, ln1b, Hb);

  // 3-5. QKV projections
  gemm_bt_kern<1, 0, 0><<<dim3(16, 32), 256, 0, stream>>>(Hb, WQT, bq, nullptr, Qb,   MROWS, DMODEL, DMODEL);
  gemm_bt_kern<1, 0, 0><<<dim3(16, 32), 256, 0, stream>>>(Hb, WKT, bk, nullptr, Kbuf, MROWS, DMODEL, DMODEL);
  gemm_bt_kern<1, 0, 0><<<dim3(16, 32), 256, 0, stream>>>(Hb, WVT, bv, nullptr, Vb,   MROWS, DMODEL, DMODEL);

  // 6. attention stats (upper-tri exp row sums + diagonal)
  attn_stats_kern<<<dim3(32, 32), 256, 0, stream>>>(Qb, Kbuf, Eb, DGb);

  // 7. V prefix machinery + combine -> attn (into Hb, h is dead)
  vchunk_kern<<<dim3(32, 32), 128, 0, stream>>>(Vb, CSb);
  attn_combine_kern<<<dim3(32, 32), 128, 0, stream>>>(Vb, CSb, Eb, DGb, Hb);

  // 8. O projection + residual(x) -> X2 (fp32)
  gemm_bt_kern<0, 0, 1><<<dim3(16, 32), 256, 0, stream>>>(Hb, WOT, bo, x, X2, MROWS, DMODEL, DMODEL);

  // 9. LN2: X2 -> h2 (bf16, reuse Hb)
  ln_kern<<<MROWS, 256, 0, stream>>>(X2, ln2g, ln2b, Hb);

  // 10. FF1 + ReLU -> F1 (bf16)
  gemm_bt_kern<1, 1, 0><<<dim3(64, 32), 256, 0, stream>>>(Hb, W1T, b1, nullptr, F1, MROWS, DFFN, DMODEL);

  // 11. FF2 + residual(X2) -> out (fp32)
  gemm_bt_kern<0, 0, 1><<<dim3(16, 32), 256, 0, stream>>>(F1, W2T, b2, X2, out, MROWS, DMODEL, DFFN);
}

// Round 4
// 743.350 us; speedup vs baseline: 1.2851x; 1.0568x over previous
//
#include <hip/hip_runtime.h>

// Decoder block, MI355X. Math note: the reference's triu/swap/softmax/triu
// masking reduces attention to:
//   denom(q) = q + sum_{k>=q} exp(scores[q,k])
//   attn[q]  = ( sum_{k<q} v[k] + exp(scores[q,q])*v[q] ) / denom(q)
// so PV is a prefix sum over V; only upper-triangular row sums of exp(QK^T/sqrt(D))
// are needed. All GEMMs run in bf16 MFMA (threshold 0.155 allows it).

typedef unsigned short ushort_t;
typedef unsigned int   uint32;
typedef __attribute__((ext_vector_type(8))) short    short8;
typedef __attribute__((ext_vector_type(8))) ushort_t ushort8;
typedef __attribute__((ext_vector_type(4))) float    f32x4;

#define BDIM   2
#define SEQ    2048
#define DMODEL 2048
#define NHEAD  16
#define DHEAD  128
#define DFFN   8192
#define MROWS  (BDIM*SEQ)   // 4096

#define GPTR(p) (const __attribute__((address_space(1))) void*)((const void*)(p))
#define SPTR(p) (__attribute__((address_space(3))) void*)((void*)(p))

__device__ __forceinline__ float bf2f(ushort_t u) {
  union { uint32 i; float f; } c; c.i = ((uint32)u) << 16; return c.f;
}
__device__ __forceinline__ ushort_t f2bf(float f) {
  union { float f; uint32 i; } c; c.f = f;
  uint32 u = c.i;
  return (ushort_t)((u + 0x7fffu + ((u >> 16) & 1u)) >> 16);
}

// ---------------- weight transpose fp32[K][N] -> bf16[N][K] ----------------
__global__ __launch_bounds__(256) void transpose_f32_bf16_kern(
    const float* __restrict__ W, ushort_t* __restrict__ Wt, int K, int N)
{
  __shared__ float tile[32][33];
  const int nb = blockIdx.x * 32, kb = blockIdx.y * 32;
  const int tx = threadIdx.x & 31, ty = threadIdx.x >> 5;   // ty: 0..7
#pragma unroll
  for (int j = 0; j < 32; j += 8)
    tile[ty + j][tx] = W[(size_t)(kb + ty + j) * N + nb + tx];
  __syncthreads();
#pragma unroll
  for (int j = 0; j < 32; j += 8)
    Wt[(size_t)(nb + ty + j) * K + kb + tx] = f2bf(tile[tx][ty + j]);
}

// ---------------- LayerNorm fp32 -> bf16, one block per row ----------------
__global__ __launch_bounds__(256) void ln_kern(
    const float* __restrict__ X, const float* __restrict__ G,
    const float* __restrict__ Bb, ushort_t* __restrict__ Out)
{
  const int row = blockIdx.x, tid = threadIdx.x;
  const float* xr = X + (size_t)row * DMODEL;
  float4 v0 = ((const float4*)xr)[tid * 2];
  float4 v1 = ((const float4*)xr)[tid * 2 + 1];
  float s  = v0.x + v0.y + v0.z + v0.w + v1.x + v1.y + v1.z + v1.w;
  float ss = v0.x*v0.x + v0.y*v0.y + v0.z*v0.z + v0.w*v0.w
           + v1.x*v1.x + v1.y*v1.y + v1.z*v1.z + v1.w*v1.w;
#pragma unroll
  for (int off = 32; off > 0; off >>= 1) {
    s  += __shfl_down(s, off);
    ss += __shfl_down(ss, off);
  }
  __shared__ float rs[4], rss[4];
  __shared__ float sh_mu, sh_rst;
  const int wv = tid >> 6;
  if ((tid & 63) == 0) { rs[wv] = s; rss[wv] = ss; }
  __syncthreads();
  if (tid == 0) {
    float S1 = rs[0] + rs[1] + rs[2] + rs[3];
    float S2 = rss[0] + rss[1] + rss[2] + rss[3];
    float mu = S1 * (1.f / DMODEL);
    float var = S2 * (1.f / DMODEL) - mu * mu;
    sh_mu = mu;
    sh_rst = rsqrtf(var + 1e-5f);
  }
  __syncthreads();
  const float mu = sh_mu, rst = sh_rst;
  float4 g0 = ((const float4*)G)[tid * 2];
  float4 g1 = ((const float4*)G)[tid * 2 + 1];
  float4 b0 = ((const float4*)Bb)[tid * 2];
  float4 b1 = ((const float4*)Bb)[tid * 2 + 1];
  ushort8 o;
  o[0] = f2bf((v0.x - mu) * rst * g0.x + b0.x);
  o[1] = f2bf((v0.y - mu) * rst * g0.y + b0.y);
  o[2] = f2bf((v0.z - mu) * rst * g0.z + b0.z);
  o[3] = f2bf((v0.w - mu) * rst * g0.w + b0.w);
  o[4] = f2bf((v1.x - mu) * rst * g1.x + b1.x);
  o[5] = f2bf((v1.y - mu) * rst * g1.y + b1.y);
  o[6] = f2bf((v1.z - mu) * rst * g1.z + b1.z);
  o[7] = f2bf((v1.w - mu) * rst * g1.w + b1.w);
  *(ushort8*)(Out + (size_t)row * DMODEL + tid * 8) = o;
}

// ---------------- pipelined GEMM: C[M,N] = A * Bt^T + bias -----------------
// BM=128, BN=256, BK=32; 512 thr = 8 waves (2Mx4N), per-wave 64x64 out.
// 3-buffer LDS ring (72 KB), stage tile t+2 while computing tile t.
// Counted vmcnt(3) once per tile (never 0 in steady state); chunk-XOR LDS
// swizzle (chunk ^= (row>>1)&3) via pre-swizzled GLOBAL source (LDS linear)
// and the same XOR on ds_read addresses -> 2-way banks (free).
template<int OUT_BF16, int RELU, int RESID>
__global__ __launch_bounds__(512, 2) void gemm_pipe_kern(
    const ushort_t* __restrict__ A, const ushort_t* __restrict__ Bt,
    const float* __restrict__ bias, const float* __restrict__ resid,
    void* __restrict__ Cout, int M, int N, int K)
{
  __shared__ ushort_t sA[3 * 128 * 32];   // 3 x 8 KB
  __shared__ ushort_t sB[3 * 256 * 32];   // 3 x 16 KB

  const int tid = threadIdx.x;
  // bijective XCD swizzle on flattened block id (grids are %8 == 0)
  const int nbx = gridDim.x;
  const int nwg = nbx * gridDim.y;
  const int bid = blockIdx.y * nbx + blockIdx.x;
  const int cpx = nwg >> 3;
  const int swz = (bid & 7) * cpx + (bid >> 3);
  const int n0 = (swz % nbx) * 256;
  const int m0 = (swz / nbx) * 128;

  const int l  = tid & 63, w = tid >> 6;
  const int lr = l & 15, lg = l >> 4;
  const int wr = w >> 2, wc = w & 3;          // wave tile: (wr*64, wc*64)

  // ---- staging source pointers (pre-swizzled chunk) ----
  const int srow = tid >> 2;                          // 0..127
  const int schunk = ((tid & 3) ^ ((tid >> 3) & 3)) * 8;
  const ushort_t* Asrc  = A  + (size_t)(m0 + srow) * K + schunk;
  const ushort_t* Bsrc0 = Bt + (size_t)(n0 + srow) * K + schunk;
  const ushort_t* Bsrc1 = Bt + (size_t)(n0 + 128 + srow) * K + schunk;
  ushort_t* sAd = sA + tid * 8;                       // + buf*4096
  ushort_t* sBd = sB + tid * 8;                       // + buf*8192 (+4096 for B1)

  // ---- read-side addresses (ushort units) ----
  const int rdoff = ((lg ^ ((lr >> 1) & 3))) * 8;     // swizzled chunk
  const int arow = (wr * 64 + lr) * 32 + rdoff;       // + mi*512, + buf*4096
  const int brow = (wc * 64 + lr) * 32 + rdoff;       // + ni*512, + buf*8192

  f32x4 acc[4][4] = {};
  const int T = K >> 5;

#define STAGE_AB0(d, kt) do { \
    __builtin_amdgcn_global_load_lds(GPTR(Asrc  + (size_t)(kt) * 32), SPTR(sAd + (d) * 4096), 16, 0, 0); \
    __builtin_amdgcn_global_load_lds(GPTR(Bsrc0 + (size_t)(kt) * 32), SPTR(sBd + (d) * 8192), 16, 0, 0); \
  } while (0)
#define STAGE_B1(d, kt) \
    __builtin_amdgcn_global_load_lds(GPTR(Bsrc1 + (size_t)(kt) * 32), SPTR(sBd + (d) * 8192 + 4096), 16, 0, 0)

  // prologue: stage tiles 0,1
  STAGE_AB0(0, 0); STAGE_B1(0, 0);
  STAGE_AB0(1, 1); STAGE_B1(1, 1);
  asm volatile("s_waitcnt vmcnt(3)" ::: "memory");    // tile0 landed
  __builtin_amdgcn_s_barrier();
  __builtin_amdgcn_sched_barrier(0);

  int cur = 0;
  for (int t = 0; t < T; ++t) {
    const int nxt2 = (cur == 0) ? 2 : cur - 1;        // (cur+2)%3
    const ushort_t* pA = sA + cur * 4096;
    const ushort_t* pB = sB + cur * 8192;

    // ---- phase 0: read A(mi0-3)+B(ni0-1); stage A,B0 of t+2; MFMA ni0-1 ----
    short8 af0 = *(const short8*)(pA + arow);
    short8 af1 = *(const short8*)(pA + arow + 512);
    short8 af2 = *(const short8*)(pA + arow + 1024);
    short8 af3 = *(const short8*)(pA + arow + 1536);
    short8 bf0 = *(const short8*)(pB + brow);
    short8 bf1 = *(const short8*)(pB + brow + 512);
    if (t + 2 < T) STAGE_AB0(nxt2, t + 2);
    __builtin_amdgcn_s_barrier();
    asm volatile("s_waitcnt lgkmcnt(0)" ::: "memory");
    __builtin_amdgcn_sched_barrier(0);
    __builtin_amdgcn_s_setprio(1);
    acc[0][0] = __builtin_amdgcn_mfma_f32_16x16x32_bf16(af0, bf0, acc[0][0], 0, 0, 0);
    acc[1][0] = __builtin_amdgcn_mfma_f32_16x16x32_bf16(af1, bf0, acc[1][0], 0, 0, 0);
    acc[2][0] = __builtin_amdgcn_mfma_f32_16x16x32_bf16(af2, bf0, acc[2][0], 0, 0, 0);
    acc[3][0] = __builtin_amdgcn_mfma_f32_16x16x32_bf16(af3, bf0, acc[3][0], 0, 0, 0);
    acc[0][1] = __builtin_amdgcn_mfma_f32_16x16x32_bf16(af0, bf1, acc[0][1], 0, 0, 0);
    acc[1][1] = __builtin_amdgcn_mfma_f32_16x16x32_bf16(af1, bf1, acc[1][1], 0, 0, 0);
    acc[2][1] = __builtin_amdgcn_mfma_f32_16x16x32_bf16(af2, bf1, acc[2][1], 0, 0, 0);
    acc[3][1] = __builtin_amdgcn_mfma_f32_16x16x32_bf16(af3, bf1, acc[3][1], 0, 0, 0);
    __builtin_amdgcn_s_setprio(0);
    __builtin_amdgcn_s_barrier();

    // ---- phase 1: read B(ni2-3); stage B1 of t+2; MFMA ni2-3 ----
    short8 bf2 = *(const short8*)(pB + brow + 1024);
    short8 bf3 = *(const short8*)(pB + brow + 1536);
    if (t + 2 < T) STAGE_B1(nxt2, t + 2);
    __builtin_amdgcn_s_barrier();
    asm volatile("s_waitcnt lgkmcnt(0)" ::: "memory");
    __builtin_amdgcn_sched_barrier(0);
    __builtin_amdgcn_s_setprio(1);
    acc[0][2] = __builtin_amdgcn_mfma_f32_16x16x32_bf16(af0, bf2, acc[0][2], 0, 0, 0);
    acc[1][2] = __builtin_amdgcn_mfma_f32_16x16x32_bf16(af1, bf2, acc[1][2], 0, 0, 0);
    acc[2][2] = __builtin_amdgcn_mfma_f32_16x16x32_bf16(af2, bf2, acc[2][2], 0, 0, 0);
    acc[3][2] = __builtin_amdgcn_mfma_f32_16x16x32_bf16(af3, bf2, acc[3][2], 0, 0, 0);
    acc[0][3] = __builtin_amdgcn_mfma_f32_16x16x32_bf16(af0, bf3, acc[0][3], 0, 0, 0);
    acc[1][3] = __builtin_amdgcn_mfma_f32_16x16x32_bf16(af1, bf3, acc[1][3], 0, 0, 0);
    acc[2][3] = __builtin_amdgcn_mfma_f32_16x16x32_bf16(af2, bf3, acc[2][3], 0, 0, 0);
    acc[3][3] = __builtin_amdgcn_mfma_f32_16x16x32_bf16(af3, bf3, acc[3][3], 0, 0, 0);
    __builtin_amdgcn_s_setprio(0);
    // tile t+1's loads must be landed before next tile reads it:
    if (t + 2 < T) { asm volatile("s_waitcnt vmcnt(3)" ::: "memory"); }
    else           { asm volatile("s_waitcnt vmcnt(0)" ::: "memory"); }
    __builtin_amdgcn_s_barrier();
    __builtin_amdgcn_sched_barrier(0);
    cur = (cur == 2) ? 0 : cur + 1;
  }
#undef STAGE_AB0
#undef STAGE_B1

  // ---- epilogue ----
#pragma unroll
  for (int mi = 0; mi < 4; ++mi) {
#pragma unroll
    for (int ni = 0; ni < 4; ++ni) {
      const int gn = n0 + wc * 64 + ni * 16 + lr;
      const float bvv = bias[gn];
#pragma unroll
      for (int j = 0; j < 4; ++j) {
        const int gm = m0 + wr * 64 + mi * 16 + lg * 4 + j;
        float v = acc[mi][ni][j] + bvv;
        if (RESID) v += resid[(size_t)gm * N + gn];
        if (RELU) v = fmaxf(v, 0.f);
        if (OUT_BF16) ((ushort_t*)Cout)[(size_t)gm * N + gn] = f2bf(v);
        else          ((float*)Cout)[(size_t)gm * N + gn] = v;
      }
    }
  }
}

// ---------------- attention stats v2 ---------------------------------------
// E[q] = sum_{k>=q} exp(s[q,k]*scale), DG[q] = exp(s[q,q]*scale).
// 256 threads = 4 waves; block owns 64 q-rows of one (b,h); K staged in LDS
// 64 rows at a time via global_load_lds with chunk-XOR swizzle.
__global__ __launch_bounds__(256) void attn_stats_kern(
    const ushort_t* __restrict__ Q, const ushort_t* __restrict__ Kb,
    float* __restrict__ E, float* __restrict__ DG)
{
  __shared__ ushort_t Ksm[64 * 128];   // 16 KB
  const int qb = blockIdx.x;           // 0..31 -> q rows [qb*64, qb*64+64)
  const int bh = blockIdx.y;           // 0..31
  const int b = bh >> 4, h = bh & 15;
  const int tid = threadIdx.x;
  const int l = tid & 63, w = tid >> 6;
  const int lr = l & 15, lg = l >> 4;

  const int qrow0 = qb * 64 + w * 16;  // wave's q-subtile

  const size_t qoff = (size_t)(b * SEQ + qrow0 + lr) * DMODEL + h * DHEAD + lg * 8;
  short8 af[4];
#pragma unroll
  for (int c = 0; c < 4; ++c) af[c] = *(const short8*)(Q + qoff + c * 32);

  const int srow_b = w * 16 + (l >> 4);           // + c*4
  const ushort_t* Kg = Kb + (size_t)b * SEQ * DMODEL + (size_t)h * DHEAD;
  ushort_t* Sbase = Ksm + w * 2048;               // + c*512 (ushort units)

  f32x4 sume = {0.f, 0.f, 0.f, 0.f};
  f32x4 dge  = {0.f, 0.f, 0.f, 0.f};
  const float scale = 0.0220970869120796f;        // 1/sqrt(2048)
  const int rx = lr & 7;                          // read-side xor key

  for (int kc = qb; kc < 32; ++kc) {
    __syncthreads();
#pragma unroll
    for (int c = 0; c < 4; ++c) {
      const int row = srow_b + c * 4;
      const int g = (l & 15) ^ (row & 7);
      __builtin_amdgcn_global_load_lds(
          GPTR(Kg + (size_t)(kc * 64 + row) * DMODEL + g * 8),
          SPTR(Sbase + c * 512), 16, 0, 0);
    }
    __syncthreads();

    const int ks0 = (kc == qb) ? w : 0;           // skip fully-masked subtiles
    for (int ks = ks0; ks < 4; ++ks) {
      short8 bfr[4];
#pragma unroll
      for (int c = 0; c < 4; ++c)
        bfr[c] = *(const short8*)(Ksm + (ks * 16 + lr) * 128 + ((lg + c * 4) ^ rx) * 8);
      f32x4 sc = {0.f, 0.f, 0.f, 0.f};
      sc = __builtin_amdgcn_mfma_f32_16x16x32_bf16(af[0], bfr[0], sc, 0, 0, 0);
      sc = __builtin_amdgcn_mfma_f32_16x16x32_bf16(af[1], bfr[1], sc, 0, 0, 0);
      sc = __builtin_amdgcn_mfma_f32_16x16x32_bf16(af[2], bfr[2], sc, 0, 0, 0);
      sc = __builtin_amdgcn_mfma_f32_16x16x32_bf16(af[3], bfr[3], sc, 0, 0, 0);
      if (kc == qb && ks == w) {
        const int ki = kc * 64 + ks * 16 + lr;
#pragma unroll
        for (int j = 0; j < 4; ++j) {
          const int qi = qrow0 + lg * 4 + j;
          if (ki >= qi) {
            float e = __expf(sc[j] * scale);
            sume[j] += e;
            if (ki == qi) dge[j] += e;
          }
        }
      } else {
#pragma unroll
        for (int j = 0; j < 4; ++j)
          sume[j] += __expf(sc[j] * scale);
      }
    }
  }

#pragma unroll
  for (int j = 0; j < 4; ++j) {
#pragma unroll
    for (int off = 1; off < 16; off <<= 1) {
      sume[j] += __shfl_xor(sume[j], off);
      dge[j]  += __shfl_xor(dge[j], off);
    }
  }
  if (lr == 0) {
#pragma unroll
    for (int j = 0; j < 4; ++j) {
      E[(size_t)bh * SEQ + qrow0 + lg * 4 + j]  = sume[j];
      DG[(size_t)bh * SEQ + qrow0 + lg * 4 + j] = dge[j];
    }
  }
}

// ---------------- V chunk sums (64-row chunks) -----------------------------
__global__ __launch_bounds__(128) void vchunk_kern(
    const ushort_t* __restrict__ V, float* __restrict__ CS)
{
  const int c = blockIdx.x, bh = blockIdx.y;
  const int b = bh >> 4, h = bh & 15;
  const int dh = threadIdx.x;
  const ushort_t* vp = V + (size_t)(b * SEQ + c * 64) * DMODEL + h * DHEAD + dh;
  float s = 0.f;
  for (int i = 0; i < 64; ++i) s += bf2f(vp[(size_t)i * DMODEL]);
  CS[((size_t)bh * 32 + c) * 128 + dh] = s;
}

// ---------------- combine: attn = (prefixV + diag*v)/denom -> bf16 ---------
__global__ __launch_bounds__(128) void attn_combine_kern(
    const ushort_t* __restrict__ V, const float* __restrict__ CS,
    const float* __restrict__ E, const float* __restrict__ DG,
    ushort_t* __restrict__ Attn)
{
  const int c = blockIdx.x, bh = blockIdx.y;
  const int b = bh >> 4, h = bh & 15;
  const int dh = threadIdx.x;
  float prefix = 0.f;
  for (int cc = 0; cc < c; ++cc) prefix += CS[((size_t)bh * 32 + cc) * 128 + dh];
  const ushort_t* vp = V + (size_t)(b * SEQ + c * 64) * DMODEL + h * DHEAD + dh;
  ushort_t* ap = Attn + (size_t)(b * SEQ + c * 64) * DMODEL + h * DHEAD + dh;
  const int qb = c * 64;
  for (int i = 0; i < 64; ++i) {
    const int qq = qb + i;
    const float denom = (float)qq + E[(size_t)bh * SEQ + qq];
    const float de = DG[(size_t)bh * SEQ + qq];
    const float vv = bf2f(vp[(size_t)i * DMODEL]);
    ap[(size_t)i * DMODEL] = f2bf((prefix + de * vv) / denom);
    prefix += vv;
  }
}

// ---------------------------------------------------------------------------
extern "C" void kernel_launch(void* const* d_in, const int* in_sizes, int n_in,
                              void* d_out, int out_size, void* d_ws, size_t ws_size,
                              hipStream_t stream)
{
  const float* x    = (const float*)d_in[0];
  const float* wq   = (const float*)d_in[1];
  const float* bq   = (const float*)d_in[2];
  const float* wk   = (const float*)d_in[3];
  const float* bk   = (const float*)d_in[4];
  const float* wv   = (const float*)d_in[5];
  const float* bv   = (const float*)d_in[6];
  const float* wo   = (const float*)d_in[7];
  const float* bo   = (const float*)d_in[8];
  const float* ln1g = (const float*)d_in[9];
  const float* ln1b = (const float*)d_in[10];
  const float* w1   = (const float*)d_in[11];
  const float* b1   = (const float*)d_in[12];
  const float* w2   = (const float*)d_in[13];
  const float* b2   = (const float*)d_in[14];
  const float* ln2g = (const float*)d_in[15];
  const float* ln2b = (const float*)d_in[16];
  float* out = (float*)d_out;

  // ws layout (bytes). F1 pool reuses regions dead by the time FF1 runs.
  char* ws = (char*)d_ws;
  ushort_t* W1T  = (ushort_t*)(ws + 0);            // 33554432
  ushort_t* W2T  = (ushort_t*)(ws + 33554432);     // 33554432
  ushort_t* WOT  = (ushort_t*)(ws + 67108864);     //  8388608
  float*    X2   = (float*)   (ws + 75497472);     // 33554432
  ushort_t* Hb   = (ushort_t*)(ws + 109051904);    // 16777216 (h / attn / h2)
  ushort_t* F1   = (ushort_t*)(ws + 125829120);    // 67108864 (overlaps below)
  ushort_t* WQT  = (ushort_t*)(ws + 125829120);    //  8388608
  ushort_t* WKT  = (ushort_t*)(ws + 134217728);    //  8388608
  ushort_t* WVT  = (ushort_t*)(ws + 142606336);    //  8388608
  ushort_t* Qb   = (ushort_t*)(ws + 150994944);    // 16777216
  ushort_t* Kbuf = (ushort_t*)(ws + 167772160);    // 16777216
  ushort_t* Vb   = (ushort_t*)(ws + 184549376);    // 16777216
  float*    Eb   = (float*)   (ws + 201326592);    //   262144
  float*    DGb  = (float*)   (ws + 201588736);    //   262144
  float*    CSb  = (float*)   (ws + 201850880);    //   524288  (end ~193 MiB)

  // 1. weight transposes (fp32 -> bf16 [N][K])
  transpose_f32_bf16_kern<<<dim3(64, 64),  256, 0, stream>>>(wq, WQT, 2048, 2048);
  transpose_f32_bf16_kern<<<dim3(64, 64),  256, 0, stream>>>(wk, WKT, 2048, 2048);
  transpose_f32_bf16_kern<<<dim3(64, 64),  256, 0, stream>>>(wv, WVT, 2048, 2048);
  transpose_f32_bf16_kern<<<dim3(64, 64),  256, 0, stream>>>(wo, WOT, 2048, 2048);
  transpose_f32_bf16_kern<<<dim3(256, 64), 256, 0, stream>>>(w1, W1T, 2048, 8192);
  transpose_f32_bf16_kern<<<dim3(64, 256), 256, 0, stream>>>(w2, W2T, 8192, 2048);

  // 2. LN1: x -> h (bf16)
  ln_kern<<<MROWS, 256, 0, stream>>>(x, ln1g, ln1b, Hb);

  // 3-5. QKV projections (grid 8x32 = 256 blocks each)
  gemm_pipe_kern<1, 0, 0><<<dim3(8, 32), 512, 0, stream>>>(Hb, WQT, bq, nullptr, Qb,   MROWS, DMODEL, DMODEL);
  gemm_pipe_kern<1, 0, 0><<<dim3(8, 32), 512, 0, stream>>>(Hb, WKT, bk, nullptr, Kbuf, MROWS, DMODEL, DMODEL);
  gemm_pipe_kern<1, 0, 0><<<dim3(8, 32), 512, 0, stream>>>(Hb, WVT, bv, nullptr, Vb,   MROWS, DMODEL, DMODEL);

  // 6. attention stats (upper-tri exp row sums + diagonal)
  attn_stats_kern<<<dim3(32, 32), 256, 0, stream>>>(Qb, Kbuf, Eb, DGb);

  // 7. V prefix machinery + combine -> attn (into Hb, h is dead)
  vchunk_kern<<<dim3(32, 32), 128, 0, stream>>>(Vb, CSb);
  attn_combine_kern<<<dim3(32, 32), 128, 0, stream>>>(Vb, CSb, Eb, DGb, Hb);

  // 8. O projection + residual(x) -> X2 (fp32)
  gemm_pipe_kern<0, 0, 1><<<dim3(8, 32), 512, 0, stream>>>(Hb, WOT, bo, x, X2, MROWS, DMODEL, DMODEL);

  // 9. LN2: X2 -> h2 (bf16, reuse Hb)
  ln_kern<<<MROWS, 256, 0, stream>>>(X2, ln2g, ln2b, Hb);

  // 10. FF1 + ReLU -> F1 (bf16), grid 32x32 = 1024 blocks
  gemm_pipe_kern<1, 1, 0><<<dim3(32, 32), 512, 0, stream>>>(Hb, W1T, b1, nullptr, F1, MROWS, DFFN, DMODEL);

  // 11. FF2 + residual(X2) -> out (fp32), grid 8x32 = 256 blocks
  gemm_pipe_kern<0, 0, 1><<<dim3(8, 32), 512, 0, stream>>>(F1, W2T, b2, X2, out, MROWS, DMODEL, DFFN);
}

// Round 5
// 719.551 us; speedup vs baseline: 1.3276x; 1.0331x over previous
//
#include <hip/hip_runtime.h>

// Decoder block, MI355X. Math note: the reference's triu/swap/softmax/triu
// masking reduces attention to:
//   denom(q) = q + sum_{k>=q} exp(scores[q,k])
//   attn[q]  = ( sum_{k<q} v[k] + exp(scores[q,q])*v[q] ) / denom(q)
// so PV is a prefix sum over V; only upper-triangular row sums of exp(QK^T/sqrt(D))
// are needed. All GEMMs run in bf16 MFMA (threshold 0.155 allows it).

typedef unsigned short ushort_t;
typedef unsigned int   uint32;
typedef __attribute__((ext_vector_type(8))) short    short8;
typedef __attribute__((ext_vector_type(8))) ushort_t ushort8;
typedef __attribute__((ext_vector_type(4))) float    f32x4;

#define BDIM   2
#define SEQ    2048
#define DMODEL 2048
#define NHEAD  16
#define DHEAD  128
#define DFFN   8192
#define MROWS  (BDIM*SEQ)   // 4096
#define LDQKV  6144         // fused QKV row stride

#define GPTR(p) (const __attribute__((address_space(1))) void*)((const void*)(p))
#define SPTR(p) (__attribute__((address_space(3))) void*)((void*)(p))

__device__ __forceinline__ float bf2f(ushort_t u) {
  union { uint32 i; float f; } c; c.i = ((uint32)u) << 16; return c.f;
}
__device__ __forceinline__ ushort_t f2bf(float f) {
  union { float f; uint32 i; } c; c.f = f;
  uint32 u = c.i;
  return (ushort_t)((u + 0x7fffu + ((u >> 16) & 1u)) >> 16);
}

// ---------------- weight transpose fp32[K][N] -> bf16[N][K] ----------------
__global__ __launch_bounds__(256) void transpose_f32_bf16_kern(
    const float* __restrict__ W, ushort_t* __restrict__ Wt, int K, int N)
{
  __shared__ float tile[32][33];
  const int nb = blockIdx.x * 32, kb = blockIdx.y * 32;
  const int tx = threadIdx.x & 31, ty = threadIdx.x >> 5;   // ty: 0..7
#pragma unroll
  for (int j = 0; j < 32; j += 8)
    tile[ty + j][tx] = W[(size_t)(kb + ty + j) * N + nb + tx];
  __syncthreads();
#pragma unroll
  for (int j = 0; j < 32; j += 8)
    Wt[(size_t)(nb + ty + j) * K + kb + tx] = f2bf(tile[tx][ty + j]);
}

// ---------------- bias concat (bq|bk|bv) -> 6144 ---------------------------
__global__ __launch_bounds__(256) void bias_concat_kern(
    const float* __restrict__ a, const float* __restrict__ b,
    const float* __restrict__ c, float* __restrict__ o)
{
  const int i = blockIdx.x * 256 + threadIdx.x;
  o[i] = (i < 2048) ? a[i] : ((i < 4096) ? b[i - 2048] : c[i - 4096]);
}

// ---------------- LayerNorm fp32 -> bf16, one block per row ----------------
__global__ __launch_bounds__(256) void ln_kern(
    const float* __restrict__ X, const float* __restrict__ G,
    const float* __restrict__ Bb, ushort_t* __restrict__ Out)
{
  const int row = blockIdx.x, tid = threadIdx.x;
  const float* xr = X + (size_t)row * DMODEL;
  float4 v0 = ((const float4*)xr)[tid * 2];
  float4 v1 = ((const float4*)xr)[tid * 2 + 1];
  float s  = v0.x + v0.y + v0.z + v0.w + v1.x + v1.y + v1.z + v1.w;
  float ss = v0.x*v0.x + v0.y*v0.y + v0.z*v0.z + v0.w*v0.w
           + v1.x*v1.x + v1.y*v1.y + v1.z*v1.z + v1.w*v1.w;
#pragma unroll
  for (int off = 32; off > 0; off >>= 1) {
    s  += __shfl_down(s, off);
    ss += __shfl_down(ss, off);
  }
  __shared__ float rs[4], rss[4];
  __shared__ float sh_mu, sh_rst;
  const int wv = tid >> 6;
  if ((tid & 63) == 0) { rs[wv] = s; rss[wv] = ss; }
  __syncthreads();
  if (tid == 0) {
    float S1 = rs[0] + rs[1] + rs[2] + rs[3];
    float S2 = rss[0] + rss[1] + rss[2] + rss[3];
    float mu = S1 * (1.f / DMODEL);
    float var = S2 * (1.f / DMODEL) - mu * mu;
    sh_mu = mu;
    sh_rst = rsqrtf(var + 1e-5f);
  }
  __syncthreads();
  const float mu = sh_mu, rst = sh_rst;
  float4 g0 = ((const float4*)G)[tid * 2];
  float4 g1 = ((const float4*)G)[tid * 2 + 1];
  float4 b0 = ((const float4*)Bb)[tid * 2];
  float4 b1 = ((const float4*)Bb)[tid * 2 + 1];
  ushort8 o;
  o[0] = f2bf((v0.x - mu) * rst * g0.x + b0.x);
  o[1] = f2bf((v0.y - mu) * rst * g0.y + b0.y);
  o[2] = f2bf((v0.z - mu) * rst * g0.z + b0.z);
  o[3] = f2bf((v0.w - mu) * rst * g0.w + b0.w);
  o[4] = f2bf((v1.x - mu) * rst * g1.x + b1.x);
  o[5] = f2bf((v1.y - mu) * rst * g1.y + b1.y);
  o[6] = f2bf((v1.z - mu) * rst * g1.z + b1.z);
  o[7] = f2bf((v1.w - mu) * rst * g1.w + b1.w);
  *(ushort8*)(Out + (size_t)row * DMODEL + tid * 8) = o;
}

// ---------------- pipelined GEMM: C[M,N] = A * Bt^T + bias -----------------
// BM=128, BN=256, BK=64; 512 thr = 8 waves (2Mx4N), per-wave 64x64 out.
// Ring-3 LDS (144 KB): stage tile t+2 while computing t; counted vmcnt(6)
// once per tile (6 loads/tile, never drained in steady state).
// Chunk-XOR swizzle (chunk ^= row&7 over 8x16B chunks) applied on the
// pre-swizzled GLOBAL source (LDS dest linear) + same XOR on ds_read.
// n-major XCD grouping: blocks sharing a B-panel land on one XCD (L2-resident
// B staging).
template<int OUT_BF16, int RELU, int RESID>
__global__ __launch_bounds__(512) void gemm_pipe_kern(
    const ushort_t* __restrict__ A, const ushort_t* __restrict__ Bt,
    const float* __restrict__ bias, const float* __restrict__ resid,
    void* __restrict__ Cout, int M, int N, int K)
{
  __shared__ ushort_t sA[3 * 128 * 64];   // 48 KB
  __shared__ ushort_t sB[3 * 256 * 64];   // 96 KB

  const int tid = threadIdx.x;
  // bijective XCD swizzle, n-major within each XCD chunk (nwg % 8 == 0)
  const int nM  = gridDim.y;
  const int nwg = gridDim.x * nM;
  const int bid = blockIdx.y * gridDim.x + blockIdx.x;
  const int cpx = nwg >> 3;
  const int swz = (bid & 7) * cpx + (bid >> 3);
  const int m0 = (swz % nM) * 128;
  const int n0 = (swz / nM) * 256;

  const int l  = tid & 63, w = tid >> 6;
  const int lr = l & 15, lg = l >> 4;
  const int wr = w >> 2, wc = w & 3;          // wave tile: (wr*64, wc*64)

  // ---- staging: round r covers rows r*64+(tid>>3), chunk tid&7 (16B) ----
  const int srow  = tid >> 3;                 // 0..63
  const int schunk = (tid & 7) ^ (srow & 7);  // pre-swizzled source chunk
  const ushort_t* Asrc = A  + (size_t)(m0 + srow) * K + schunk * 8;
  const ushort_t* Bsrc = Bt + (size_t)(n0 + srow) * K + schunk * 8;
  ushort_t* sAd = sA + tid * 8;               // + buf*8192 + r*4096
  ushort_t* sBd = sB + tid * 8;               // + buf*16384 + r*4096

  // ---- read-side (ushort offsets); read chunk = (kk*4+lg) ^ (lr&7) ----
  const int rxk  = lr & 7;
  const int aoff = (wr * 64 + lr) * 64;       // + mi*1024
  const int boff = (wc * 64 + lr) * 64;       // + ni*1024

  f32x4 acc[4][4] = {};
  const int T = K >> 6;

#define STAGE_A(d, kt, r) __builtin_amdgcn_global_load_lds( \
    GPTR(Asrc + (size_t)(kt) * 64 + (size_t)(r) * 64 * K), \
    SPTR(sAd + (d) * 8192 + (r) * 4096), 16, 0, 0)
#define STAGE_B(d, kt, r) __builtin_amdgcn_global_load_lds( \
    GPTR(Bsrc + (size_t)(kt) * 64 + (size_t)(r) * 64 * K), \
    SPTR(sBd + (d) * 16384 + (r) * 4096), 16, 0, 0)

  // prologue: stage tiles 0,1 (6 loads each)
  STAGE_A(0, 0, 0); STAGE_A(0, 0, 1);
  STAGE_B(0, 0, 0); STAGE_B(0, 0, 1); STAGE_B(0, 0, 2); STAGE_B(0, 0, 3);
  STAGE_A(1, 1, 0); STAGE_A(1, 1, 1);
  STAGE_B(1, 1, 0); STAGE_B(1, 1, 1); STAGE_B(1, 1, 2); STAGE_B(1, 1, 3);
  asm volatile("s_waitcnt vmcnt(6)" ::: "memory");    // tile0 landed
  __builtin_amdgcn_s_barrier();
  __builtin_amdgcn_sched_barrier(0);

  int cur = 0;
  for (int t = 0; t < T; ++t) {
    const int nx = (cur == 0) ? 2 : cur - 1;          // (cur+2)%3
    const ushort_t* pA = sA + cur * 8192;
    const ushort_t* pB = sB + cur * 16384;
    const bool pf = (t + 2 < T);

    // ---- phase 0 (kk=0): 8 ds_read, 3 stage, 16 MFMA ----
    short8 a0 = *(const short8*)(pA + aoff +    0 + ((0 ^ rxk)) * 8 + (lg ^ 0) * 0);
    a0 = *(const short8*)(pA + aoff +    0 + ((lg ^ rxk)) * 8);
    short8 a1 = *(const short8*)(pA + aoff + 1024 + ((lg ^ rxk)) * 8);
    short8 a2 = *(const short8*)(pA + aoff + 2048 + ((lg ^ rxk)) * 8);
    short8 a3 = *(const short8*)(pA + aoff + 3072 + ((lg ^ rxk)) * 8);
    short8 b0 = *(const short8*)(pB + boff +    0 + ((lg ^ rxk)) * 8);
    short8 b1 = *(const short8*)(pB + boff + 1024 + ((lg ^ rxk)) * 8);
    short8 b2 = *(const short8*)(pB + boff + 2048 + ((lg ^ rxk)) * 8);
    short8 b3 = *(const short8*)(pB + boff + 3072 + ((lg ^ rxk)) * 8);
    if (pf) { STAGE_A(nx, t + 2, 0); STAGE_A(nx, t + 2, 1); STAGE_B(nx, t + 2, 0); }
    __builtin_amdgcn_s_barrier();
    asm volatile("s_waitcnt lgkmcnt(0)" ::: "memory");
    __builtin_amdgcn_sched_barrier(0);
    __builtin_amdgcn_s_setprio(1);
    acc[0][0] = __builtin_amdgcn_mfma_f32_16x16x32_bf16(a0, b0, acc[0][0], 0, 0, 0);
    acc[1][0] = __builtin_amdgcn_mfma_f32_16x16x32_bf16(a1, b0, acc[1][0], 0, 0, 0);
    acc[2][0] = __builtin_amdgcn_mfma_f32_16x16x32_bf16(a2, b0, acc[2][0], 0, 0, 0);
    acc[3][0] = __builtin_amdgcn_mfma_f32_16x16x32_bf16(a3, b0, acc[3][0], 0, 0, 0);
    acc[0][1] = __builtin_amdgcn_mfma_f32_16x16x32_bf16(a0, b1, acc[0][1], 0, 0, 0);
    acc[1][1] = __builtin_amdgcn_mfma_f32_16x16x32_bf16(a1, b1, acc[1][1], 0, 0, 0);
    acc[2][1] = __builtin_amdgcn_mfma_f32_16x16x32_bf16(a2, b1, acc[2][1], 0, 0, 0);
    acc[3][1] = __builtin_amdgcn_mfma_f32_16x16x32_bf16(a3, b1, acc[3][1], 0, 0, 0);
    acc[0][2] = __builtin_amdgcn_mfma_f32_16x16x32_bf16(a0, b2, acc[0][2], 0, 0, 0);
    acc[1][2] = __builtin_amdgcn_mfma_f32_16x16x32_bf16(a1, b2, acc[1][2], 0, 0, 0);
    acc[2][2] = __builtin_amdgcn_mfma_f32_16x16x32_bf16(a2, b2, acc[2][2], 0, 0, 0);
    acc[3][2] = __builtin_amdgcn_mfma_f32_16x16x32_bf16(a3, b2, acc[3][2], 0, 0, 0);
    acc[0][3] = __builtin_amdgcn_mfma_f32_16x16x32_bf16(a0, b3, acc[0][3], 0, 0, 0);
    acc[1][3] = __builtin_amdgcn_mfma_f32_16x16x32_bf16(a1, b3, acc[1][3], 0, 0, 0);
    acc[2][3] = __builtin_amdgcn_mfma_f32_16x16x32_bf16(a2, b3, acc[2][3], 0, 0, 0);
    acc[3][3] = __builtin_amdgcn_mfma_f32_16x16x32_bf16(a3, b3, acc[3][3], 0, 0, 0);
    __builtin_amdgcn_s_setprio(0);
    __builtin_amdgcn_s_barrier();

    // ---- phase 1 (kk=1): 8 ds_read, 3 stage, 16 MFMA ----
    a0 = *(const short8*)(pA + aoff +    0 + (((4 + lg) ^ rxk)) * 8);
    a1 = *(const short8*)(pA + aoff + 1024 + (((4 + lg) ^ rxk)) * 8);
    a2 = *(const short8*)(pA + aoff + 2048 + (((4 + lg) ^ rxk)) * 8);
    a3 = *(const short8*)(pA + aoff + 3072 + (((4 + lg) ^ rxk)) * 8);
    b0 = *(const short8*)(pB + boff +    0 + (((4 + lg) ^ rxk)) * 8);
    b1 = *(const short8*)(pB + boff + 1024 + (((4 + lg) ^ rxk)) * 8);
    b2 = *(const short8*)(pB + boff + 2048 + (((4 + lg) ^ rxk)) * 8);
    b3 = *(const short8*)(pB + boff + 3072 + (((4 + lg) ^ rxk)) * 8);
    if (pf) { STAGE_B(nx, t + 2, 1); STAGE_B(nx, t + 2, 2); STAGE_B(nx, t + 2, 3); }
    __builtin_amdgcn_s_barrier();
    asm volatile("s_waitcnt lgkmcnt(0)" ::: "memory");
    __builtin_amdgcn_sched_barrier(0);
    __builtin_amdgcn_s_setprio(1);
    acc[0][0] = __builtin_amdgcn_mfma_f32_16x16x32_bf16(a0, b0, acc[0][0], 0, 0, 0);
    acc[1][0] = __builtin_amdgcn_mfma_f32_16x16x32_bf16(a1, b0, acc[1][0], 0, 0, 0);
    acc[2][0] = __builtin_amdgcn_mfma_f32_16x16x32_bf16(a2, b0, acc[2][0], 0, 0, 0);
    acc[3][0] = __builtin_amdgcn_mfma_f32_16x16x32_bf16(a3, b0, acc[3][0], 0, 0, 0);
    acc[0][1] = __builtin_amdgcn_mfma_f32_16x16x32_bf16(a0, b1, acc[0][1], 0, 0, 0);
    acc[1][1] = __builtin_amdgcn_mfma_f32_16x16x32_bf16(a1, b1, acc[1][1], 0, 0, 0);
    acc[2][1] = __builtin_amdgcn_mfma_f32_16x16x32_bf16(a2, b1, acc[2][1], 0, 0, 0);
    acc[3][1] = __builtin_amdgcn_mfma_f32_16x16x32_bf16(a3, b1, acc[3][1], 0, 0, 0);
    acc[0][2] = __builtin_amdgcn_mfma_f32_16x16x32_bf16(a0, b2, acc[0][2], 0, 0, 0);
    acc[1][2] = __builtin_amdgcn_mfma_f32_16x16x32_bf16(a1, b2, acc[1][2], 0, 0, 0);
    acc[2][2] = __builtin_amdgcn_mfma_f32_16x16x32_bf16(a2, b2, acc[2][2], 0, 0, 0);
    acc[3][2] = __builtin_amdgcn_mfma_f32_16x16x32_bf16(a3, b2, acc[3][2], 0, 0, 0);
    acc[0][3] = __builtin_amdgcn_mfma_f32_16x16x32_bf16(a0, b3, acc[0][3], 0, 0, 0);
    acc[1][3] = __builtin_amdgcn_mfma_f32_16x16x32_bf16(a1, b3, acc[1][3], 0, 0, 0);
    acc[2][3] = __builtin_amdgcn_mfma_f32_16x16x32_bf16(a2, b3, acc[2][3], 0, 0, 0);
    acc[3][3] = __builtin_amdgcn_mfma_f32_16x16x32_bf16(a3, b3, acc[3][3], 0, 0, 0);
    __builtin_amdgcn_s_setprio(0);
    if (pf) { asm volatile("s_waitcnt vmcnt(6)" ::: "memory"); }
    else    { asm volatile("s_waitcnt vmcnt(0)" ::: "memory"); }
    __builtin_amdgcn_s_barrier();
    __builtin_amdgcn_sched_barrier(0);
    cur = (cur == 2) ? 0 : cur + 1;
  }
#undef STAGE_A
#undef STAGE_B

  // ---- epilogue ----
#pragma unroll
  for (int mi = 0; mi < 4; ++mi) {
#pragma unroll
    for (int ni = 0; ni < 4; ++ni) {
      const int gn = n0 + wc * 64 + ni * 16 + lr;
      const float bvv = bias[gn];
#pragma unroll
      for (int j = 0; j < 4; ++j) {
        const int gm = m0 + wr * 64 + mi * 16 + lg * 4 + j;
        float v = acc[mi][ni][j] + bvv;
        if (RESID) v += resid[(size_t)gm * N + gn];
        if (RELU) v = fmaxf(v, 0.f);
        if (OUT_BF16) ((ushort_t*)Cout)[(size_t)gm * N + gn] = f2bf(v);
        else          ((float*)Cout)[(size_t)gm * N + gn] = v;
      }
    }
  }
}

// ---------------- attention stats -----------------------------------------
// E[q] = sum_{k>=q} exp(s[q,k]*scale), DG[q] = exp(s[q,q]*scale).
// 256 threads = 4 waves; block owns 64 q-rows of one (b,h); K staged in LDS
// 64 rows at a time via global_load_lds with chunk-XOR swizzle. ld = row
// stride of Q/K (fused QKV buffer).
__global__ __launch_bounds__(256) void attn_stats_kern(
    const ushort_t* __restrict__ Q, const ushort_t* __restrict__ Kb,
    float* __restrict__ E, float* __restrict__ DG, int ld)
{
  __shared__ ushort_t Ksm[64 * 128];   // 16 KB
  const int qb = blockIdx.x;           // 0..31 -> q rows [qb*64, qb*64+64)
  const int bh = blockIdx.y;           // 0..31
  const int b = bh >> 4, h = bh & 15;
  const int tid = threadIdx.x;
  const int l = tid & 63, w = tid >> 6;
  const int lr = l & 15, lg = l >> 4;

  const int qrow0 = qb * 64 + w * 16;  // wave's q-subtile

  const size_t qoff = (size_t)(b * SEQ + qrow0 + lr) * ld + h * DHEAD + lg * 8;
  short8 af[4];
#pragma unroll
  for (int c = 0; c < 4; ++c) af[c] = *(const short8*)(Q + qoff + c * 32);

  const int srow_b = w * 16 + (l >> 4);           // + c*4
  const ushort_t* Kg = Kb + (size_t)b * SEQ * ld + (size_t)h * DHEAD;
  ushort_t* Sbase = Ksm + w * 2048;               // + c*512 (ushort units)

  f32x4 sume = {0.f, 0.f, 0.f, 0.f};
  f32x4 dge  = {0.f, 0.f, 0.f, 0.f};
  const float scale = 0.0220970869120796f;        // 1/sqrt(2048)
  const int rx = lr & 7;                          // read-side xor key

  for (int kc = qb; kc < 32; ++kc) {
    __syncthreads();
#pragma unroll
    for (int c = 0; c < 4; ++c) {
      const int row = srow_b + c * 4;
      const int g = (l & 15) ^ (row & 7);
      __builtin_amdgcn_global_load_lds(
          GPTR(Kg + (size_t)(kc * 64 + row) * ld + g * 8),
          SPTR(Sbase + c * 512), 16, 0, 0);
    }
    __syncthreads();

    const int ks0 = (kc == qb) ? w : 0;           // skip fully-masked subtiles
    for (int ks = ks0; ks < 4; ++ks) {
      short8 bfr[4];
#pragma unroll
      for (int c = 0; c < 4; ++c)
        bfr[c] = *(const short8*)(Ksm + (ks * 16 + lr) * 128 + ((lg + c * 4) ^ rx) * 8);
      f32x4 sc = {0.f, 0.f, 0.f, 0.f};
      sc = __builtin_amdgcn_mfma_f32_16x16x32_bf16(af[0], bfr[0], sc, 0, 0, 0);
      sc = __builtin_amdgcn_mfma_f32_16x16x32_bf16(af[1], bfr[1], sc, 0, 0, 0);
      sc = __builtin_amdgcn_mfma_f32_16x16x32_bf16(af[2], bfr[2], sc, 0, 0, 0);
      sc = __builtin_amdgcn_mfma_f32_16x16x32_bf16(af[3], bfr[3], sc, 0, 0, 0);
      if (kc == qb && ks == w) {
        const int ki = kc * 64 + ks * 16 + lr;
#pragma unroll
        for (int j = 0; j < 4; ++j) {
          const int qi = qrow0 + lg * 4 + j;
          if (ki >= qi) {
            float e = __expf(sc[j] * scale);
            sume[j] += e;
            if (ki == qi) dge[j] += e;
          }
        }
      } else {
#pragma unroll
        for (int j = 0; j < 4; ++j)
          sume[j] += __expf(sc[j] * scale);
      }
    }
  }

#pragma unroll
  for (int j = 0; j < 4; ++j) {
#pragma unroll
    for (int off = 1; off < 16; off <<= 1) {
      sume[j] += __shfl_xor(sume[j], off);
      dge[j]  += __shfl_xor(dge[j], off);
    }
  }
  if (lr == 0) {
#pragma unroll
    for (int j = 0; j < 4; ++j) {
      E[(size_t)bh * SEQ + qrow0 + lg * 4 + j]  = sume[j];
      DG[(size_t)bh * SEQ + qrow0 + lg * 4 + j] = dge[j];
    }
  }
}

// ---------------- V chunk sums (64-row chunks) -----------------------------
__global__ __launch_bounds__(128) void vchunk_kern(
    const ushort_t* __restrict__ V, float* __restrict__ CS, int ld)
{
  const int c = blockIdx.x, bh = blockIdx.y;
  const int b = bh >> 4, h = bh & 15;
  const int dh = threadIdx.x;
  const ushort_t* vp = V + (size_t)(b * SEQ + c * 64) * ld + h * DHEAD + dh;
  float s = 0.f;
  for (int i = 0; i < 64; ++i) s += bf2f(vp[(size_t)i * ld]);
  CS[((size_t)bh * 32 + c) * 128 + dh] = s;
}

// ---------------- combine: attn = (prefixV + diag*v)/denom -> bf16 ---------
__global__ __launch_bounds__(128) void attn_combine_kern(
    const ushort_t* __restrict__ V, const float* __restrict__ CS,
    const float* __restrict__ E, const float* __restrict__ DG,
    ushort_t* __restrict__ Attn, int ldv)
{
  const int c = blockIdx.x, bh = blockIdx.y;
  const int b = bh >> 4, h = bh & 15;
  const int dh = threadIdx.x;
  float prefix = 0.f;
  for (int cc = 0; cc < c; ++cc) prefix += CS[((size_t)bh * 32 + cc) * 128 + dh];
  const ushort_t* vp = V + (size_t)(b * SEQ + c * 64) * ldv + h * DHEAD + dh;
  ushort_t* ap = Attn + (size_t)(b * SEQ + c * 64) * DMODEL + h * DHEAD + dh;
  const int qb = c * 64;
  for (int i = 0; i < 64; ++i) {
    const int qq = qb + i;
    const float denom = (float)qq + E[(size_t)bh * SEQ + qq];
    const float de = DG[(size_t)bh * SEQ + qq];
    const float vv = bf2f(vp[(size_t)i * ldv]);
    ap[(size_t)i * DMODEL] = f2bf((prefix + de * vv) / denom);
    prefix += vv;
  }
}

// ---------------------------------------------------------------------------
extern "C" void kernel_launch(void* const* d_in, const int* in_sizes, int n_in,
                              void* d_out, int out_size, void* d_ws, size_t ws_size,
                              hipStream_t stream)
{
  const float* x    = (const float*)d_in[0];
  const float* wq   = (const float*)d_in[1];
  const float* bq   = (const float*)d_in[2];
  const float* wk   = (const float*)d_in[3];
  const float* bk   = (const float*)d_in[4];
  const float* wv   = (const float*)d_in[5];
  const float* bv   = (const float*)d_in[6];
  const float* wo   = (const float*)d_in[7];
  const float* bo   = (const float*)d_in[8];
  const float* ln1g = (const float*)d_in[9];
  const float* ln1b = (const float*)d_in[10];
  const float* w1   = (const float*)d_in[11];
  const float* b1   = (const float*)d_in[12];
  const float* w2   = (const float*)d_in[13];
  const float* b2   = (const float*)d_in[14];
  const float* ln2g = (const float*)d_in[15];
  const float* ln2b = (const float*)d_in[16];
  float* out = (float*)d_out;

  // ws layout (bytes). F1 overlaps WQKV+QKVb (dead by FF1). Bcat lives in the
  // X2 region (X2 first written at step 8, Bcat consumed at step 4).
  char* ws = (char*)d_ws;
  ushort_t* W1T  = (ushort_t*)(ws + 0);            // 33554432
  ushort_t* W2T  = (ushort_t*)(ws + 33554432);     // 33554432
  ushort_t* WOT  = (ushort_t*)(ws + 67108864);     //  8388608
  float*    X2   = (float*)   (ws + 75497472);     // 33554432 (fp32)
  float*    Bcat = (float*)   (ws + 75497472);     //    24576 (dead before X2 written)
  ushort_t* Hb   = (ushort_t*)(ws + 109051904);    // 16777216 (h / attn / h2)
  ushort_t* F1   = (ushort_t*)(ws + 125829120);    // 67108864 (overlaps below)
  ushort_t* WQKV = (ushort_t*)(ws + 125829120);    // 25165824 (6144 x 2048)
  ushort_t* QKVb = (ushort_t*)(ws + 150994944);    // 50331648 (4096 x 6144)
  float*    Eb   = (float*)   (ws + 201326592);    //   262144
  float*    DGb  = (float*)   (ws + 201588736);    //   262144
  float*    CSb  = (float*)   (ws + 201850880);    //   524288  (end ~193 MiB)

  // 1. weight transposes (fp32 -> bf16 [N][K]); wq/wk/wv stacked into WQKV
  transpose_f32_bf16_kern<<<dim3(64, 64),  256, 0, stream>>>(wq, WQKV,                 2048, 2048);
  transpose_f32_bf16_kern<<<dim3(64, 64),  256, 0, stream>>>(wk, WQKV + 2048 * 2048,   2048, 2048);
  transpose_f32_bf16_kern<<<dim3(64, 64),  256, 0, stream>>>(wv, WQKV + 2 * 2048 * 2048, 2048, 2048);
  transpose_f32_bf16_kern<<<dim3(64, 64),  256, 0, stream>>>(wo, WOT, 2048, 2048);
  transpose_f32_bf16_kern<<<dim3(256, 64), 256, 0, stream>>>(w1, W1T, 2048, 8192);
  transpose_f32_bf16_kern<<<dim3(64, 256), 256, 0, stream>>>(w2, W2T, 8192, 2048);
  bias_concat_kern<<<24, 256, 0, stream>>>(bq, bk, bv, Bcat);

  // 2. LN1: x -> h (bf16)
  ln_kern<<<MROWS, 256, 0, stream>>>(x, ln1g, ln1b, Hb);

  // 3. fused QKV projection -> QKVb [4096][6144]
  gemm_pipe_kern<1, 0, 0><<<dim3(24, 32), 512, 0, stream>>>(Hb, WQKV, Bcat, nullptr, QKVb, MROWS, LDQKV, DMODEL);

  // 4. attention stats (upper-tri exp row sums + diagonal)
  attn_stats_kern<<<dim3(32, 32), 256, 0, stream>>>(QKVb, QKVb + 2048, Eb, DGb, LDQKV);

  // 5. V prefix machinery + combine -> attn (into Hb, h is dead)
  vchunk_kern<<<dim3(32, 32), 128, 0, stream>>>(QKVb + 4096, CSb, LDQKV);
  attn_combine_kern<<<dim3(32, 32), 128, 0, stream>>>(QKVb + 4096, CSb, Eb, DGb, Hb, LDQKV);

  // 6. O projection + residual(x) -> X2 (fp32)
  gemm_pipe_kern<0, 0, 1><<<dim3(8, 32), 512, 0, stream>>>(Hb, WOT, bo, x, X2, MROWS, DMODEL, DMODEL);

  // 7. LN2: X2 -> h2 (bf16, reuse Hb)
  ln_kern<<<MROWS, 256, 0, stream>>>(X2, ln2g, ln2b, Hb);

  // 8. FF1 + ReLU -> F1 (bf16)
  gemm_pipe_kern<1, 1, 0><<<dim3(32, 32), 512, 0, stream>>>(Hb, W1T, b1, nullptr, F1, MROWS, DFFN, DMODEL);

  // 9. FF2 + residual(X2) -> out (fp32)
  gemm_pipe_kern<0, 0, 1><<<dim3(8, 32), 512, 0, stream>>>(F1, W2T, b2, X2, out, MROWS, DMODEL, DFFN);
}

// Round 7
// 654.232 us; speedup vs baseline: 1.4601x; 1.0998x over previous
//
#include <hip/hip_runtime.h>

// Decoder block, MI355X. Math note: the reference's triu/swap/softmax/triu
// masking reduces attention to:
//   denom(q) = q + sum_{k>=q} exp(scores[q,k])
//   attn[q]  = ( sum_{k<q} v[k] + exp(scores[q,q])*v[q] ) / denom(q)
// so PV is a prefix sum over V; only upper-triangular row sums of exp(QK^T/sqrt(D))
// are needed. All GEMMs run in bf16 MFMA (threshold 0.155 allows it).

typedef unsigned short ushort_t;
typedef unsigned int   uint32;
typedef __attribute__((ext_vector_type(8))) short    short8;
typedef __attribute__((ext_vector_type(8))) ushort_t ushort8;
typedef __attribute__((ext_vector_type(4))) float    f32x4;

#define BDIM   2
#define SEQ    2048
#define DMODEL 2048
#define NHEAD  16
#define DHEAD  128
#define DFFN   8192
#define MROWS  (BDIM*SEQ)   // 4096
#define LDQKV  6144         // fused QKV row stride

#define GPTR(p) (const __attribute__((address_space(1))) void*)((const void*)(p))
#define SPTR(p) (__attribute__((address_space(3))) void*)((void*)(p))

__device__ __forceinline__ float bf2f(ushort_t u) {
  union { uint32 i; float f; } c; c.i = ((uint32)u) << 16; return c.f;
}
__device__ __forceinline__ ushort_t f2bf(float f) {
  union { float f; uint32 i; } c; c.f = f;
  uint32 u = c.i;
  return (ushort_t)((u + 0x7fffu + ((u >> 16) & 1u)) >> 16);
}

// ---------------- weight transpose fp32[K][N] -> bf16[N][K] ----------------
__global__ __launch_bounds__(256) void transpose_f32_bf16_kern(
    const float* __restrict__ W, ushort_t* __restrict__ Wt, int K, int N)
{
  __shared__ float tile[32][33];
  const int nb = blockIdx.x * 32, kb = blockIdx.y * 32;
  const int tx = threadIdx.x & 31, ty = threadIdx.x >> 5;   // ty: 0..7
#pragma unroll
  for (int j = 0; j < 32; j += 8)
    tile[ty + j][tx] = W[(size_t)(kb + ty + j) * N + nb + tx];
  __syncthreads();
#pragma unroll
  for (int j = 0; j < 32; j += 8)
    Wt[(size_t)(nb + ty + j) * K + kb + tx] = f2bf(tile[tx][ty + j]);
}

// ---------------- bias concat (bq|bk|bv) -> 6144 ---------------------------
__global__ __launch_bounds__(256) void bias_concat_kern(
    const float* __restrict__ a, const float* __restrict__ b,
    const float* __restrict__ c, float* __restrict__ o)
{
  const int i = blockIdx.x * 256 + threadIdx.x;
  o[i] = (i < 2048) ? a[i] : ((i < 4096) ? b[i - 2048] : c[i - 4096]);
}

// ---------------- LayerNorm fp32 -> bf16, one block per row ----------------
__global__ __launch_bounds__(256) void ln_kern(
    const float* __restrict__ X, const float* __restrict__ G,
    const float* __restrict__ Bb, ushort_t* __restrict__ Out)
{
  const int row = blockIdx.x, tid = threadIdx.x;
  const float* xr = X + (size_t)row * DMODEL;
  float4 v0 = ((const float4*)xr)[tid * 2];
  float4 v1 = ((const float4*)xr)[tid * 2 + 1];
  float s  = v0.x + v0.y + v0.z + v0.w + v1.x + v1.y + v1.z + v1.w;
  float ss = v0.x*v0.x + v0.y*v0.y + v0.z*v0.z + v0.w*v0.w
           + v1.x*v1.x + v1.y*v1.y + v1.z*v1.z + v1.w*v1.w;
#pragma unroll
  for (int off = 32; off > 0; off >>= 1) {
    s  += __shfl_down(s, off);
    ss += __shfl_down(ss, off);
  }
  __shared__ float rs[4], rss[4];
  __shared__ float sh_mu, sh_rst;
  const int wv = tid >> 6;
  if ((tid & 63) == 0) { rs[wv] = s; rss[wv] = ss; }
  __syncthreads();
  if (tid == 0) {
    float S1 = rs[0] + rs[1] + rs[2] + rs[3];
    float S2 = rss[0] + rss[1] + rss[2] + rss[3];
    float mu = S1 * (1.f / DMODEL);
    float var = S2 * (1.f / DMODEL) - mu * mu;
    sh_mu = mu;
    sh_rst = rsqrtf(var + 1e-5f);
  }
  __syncthreads();
  const float mu = sh_mu, rst = sh_rst;
  float4 g0 = ((const float4*)G)[tid * 2];
  float4 g1 = ((const float4*)G)[tid * 2 + 1];
  float4 b0 = ((const float4*)Bb)[tid * 2];
  float4 b1 = ((const float4*)Bb)[tid * 2 + 1];
  ushort8 o;
  o[0] = f2bf((v0.x - mu) * rst * g0.x + b0.x);
  o[1] = f2bf((v0.y - mu) * rst * g0.y + b0.y);
  o[2] = f2bf((v0.z - mu) * rst * g0.z + b0.z);
  o[3] = f2bf((v0.w - mu) * rst * g0.w + b0.w);
  o[4] = f2bf((v1.x - mu) * rst * g1.x + b1.x);
  o[5] = f2bf((v1.y - mu) * rst * g1.y + b1.y);
  o[6] = f2bf((v1.z - mu) * rst * g1.z + b1.z);
  o[7] = f2bf((v1.w - mu) * rst * g1.w + b1.w);
  *(ushort8*)(Out + (size_t)row * DMODEL + tid * 8) = o;
}

// ---------------- 8-phase 256x256 GEMM (m201-style) ------------------------
// BM=BN=256, BK=64; 512 thr = 8 waves (2Mx4N), per-wave 128x64 out (8x4 frags).
// LDS 128KB = per operand [2 parity][2 kk-half][256 rows][32 k] bf16.
// Per K-tile: 4 clusters {ds_read frags; issue 2 global_load_lds; setprio(1);
// 16 MFMA; setprio(0)}; 2 barriers/tile, each preceded by counted vmcnt(8).
// Staging runs 6 phases ahead: kk1(t+1) in cl0/cl1, kk0(t+2) in cl2/cl3
// (its slot freed at this tile's mid barrier). Chunk-XOR swizzle
// (chunk ^= (row>>1)&3) via pre-swizzled global source + XOR'd ds_read.
// OUT: 0=fp32(bias+resid), 1=bf16(bias,[relu]), 2=bf16 partial (split-K,
// no bias, part z at Cout + z*M*N).
template<int OUT, int RELU, int RESID, int KDIV>
__global__ __launch_bounds__(512, 2) void gemm8_kern(
    const ushort_t* __restrict__ A, const ushort_t* __restrict__ Bt,
    const float* __restrict__ bias, const float* __restrict__ resid,
    void* __restrict__ Cout, int M, int N, int K)
{
  __shared__ ushort_t sA[4 * 8192];   // 64 KB
  __shared__ ushort_t sB[4 * 8192];   // 64 KB

  const int tid = threadIdx.x;
  // bijective XCD swizzle (x=n-blocks, y=m-blocks; nwg % 8 == 0), m-major
  const int nM  = gridDim.y;
  const int nwg = gridDim.x * nM;
  const int bid = blockIdx.y * gridDim.x + blockIdx.x;
  const int cpx = nwg >> 3;
  const int swz = (bid & 7) * cpx + (bid >> 3);
  const int m0 = (swz % nM) * 256;
  const int n0 = (swz / nM) * 256;

  const int Keff = K / KDIV;
  const int k0 = (KDIV > 1) ? blockIdx.z * Keff : 0;
  const int T = Keff >> 6;

  const int l = tid & 63, w = tid >> 6;
  const int lr = l & 15, lg = l >> 4;
  const int wr = w >> 2, wc = w & 3;

  // read-side swizzled chunk and bases (ushort units within a slot)
  const int xch   = (lg ^ ((lr >> 1) & 3)) * 8;
  const int abase = (wr * 128 + lr) * 32 + xch;   // + mi*512
  const int bbase = (wc * 64  + lr) * 32 + xch;   // + ni*512

  // staging: round covers rows r*128+(tid>>2), chunk tid&3; source pre-swizzled
  const int sr = tid >> 2;                        // 0..127
  const int sg = ((tid & 3) ^ ((tid >> 3) & 3)) * 8;
  const ushort_t* Asrc = A  + (size_t)(m0 + sr) * K + k0 + sg;
  const ushort_t* Bsrc = Bt + (size_t)(n0 + sr) * K + k0 + sg;
  ushort_t* dA = sA + tid * 8;
  ushort_t* dB = sB + tid * 8;

#define SA_(slot, kt, kk, r) __builtin_amdgcn_global_load_lds( \
    GPTR(Asrc + (size_t)(r) * 128 * K + (kt) * 64 + (kk) * 32), \
    SPTR(dA + (slot) * 8192 + (r) * 4096), 16, 0, 0)
#define SB_(slot, kt, kk, r) __builtin_amdgcn_global_load_lds( \
    GPTR(Bsrc + (size_t)(r) * 128 * K + (kt) * 64 + (kk) * 32), \
    SPTR(dB + (slot) * 8192 + (r) * 4096), 16, 0, 0)

  f32x4 acc[8][4] = {};

  // prologue: kk0(0)->slot0, kk1(0)->slot1, kk0(1)->slot2 (12 loads)
  SA_(0, 0, 0, 0); SA_(0, 0, 0, 1); SB_(0, 0, 0, 0); SB_(0, 0, 0, 1);
  SA_(1, 0, 1, 0); SA_(1, 0, 1, 1); SB_(1, 0, 1, 0); SB_(1, 0, 1, 1);
  SA_(2, 1, 0, 0); SA_(2, 1, 0, 1); SB_(2, 1, 0, 0); SB_(2, 1, 0, 1);
  asm volatile("s_waitcnt vmcnt(8)" ::: "memory");   // kk0(0) landed
  __builtin_amdgcn_s_barrier();

  for (int t = 0; t < T; ++t) {
    const int c = t & 1;
    const ushort_t* A0 = sA + (c * 2 + 0) * 8192;
    const ushort_t* B0 = sB + (c * 2 + 0) * 8192;
    const ushort_t* A1 = sA + (c * 2 + 1) * 8192;
    const ushort_t* B1 = sB + (c * 2 + 1) * 8192;
    const int s1 = (c ^ 1) * 2 + 1;     // kk1(t+1) slot (parity c^1)
    const int s0 = c * 2;               // kk0(t+2) slot (parity (t+2)&1 = c)
    const bool pf1 = (t + 1 < T), pf0 = (t + 2 < T);

    short8 a0, a1, a2, a3, b0, b1, b2, b3;

    // ---- cl0: kk0, mi0-3 x ni0-3 ----
    b0 = *(const short8*)(B0 + bbase);
    b1 = *(const short8*)(B0 + bbase + 512);
    b2 = *(const short8*)(B0 + bbase + 1024);
    b3 = *(const short8*)(B0 + bbase + 1536);
    a0 = *(const short8*)(A0 + abase);
    a1 = *(const short8*)(A0 + abase + 512);
    a2 = *(const short8*)(A0 + abase + 1024);
    a3 = *(const short8*)(A0 + abase + 1536);
    if (pf1) { SA_(s1, t + 1, 1, 0); SA_(s1, t + 1, 1, 1); }
    __builtin_amdgcn_s_setprio(1);
    acc[0][0] = __builtin_amdgcn_mfma_f32_16x16x32_bf16(a0, b0, acc[0][0], 0, 0, 0);
    acc[0][1] = __builtin_amdgcn_mfma_f32_16x16x32_bf16(a0, b1, acc[0][1], 0, 0, 0);
    acc[0][2] = __builtin_amdgcn_mfma_f32_16x16x32_bf16(a0, b2, acc[0][2], 0, 0, 0);
    acc[0][3] = __builtin_amdgcn_mfma_f32_16x16x32_bf16(a0, b3, acc[0][3], 0, 0, 0);
    acc[1][0] = __builtin_amdgcn_mfma_f32_16x16x32_bf16(a1, b0, acc[1][0], 0, 0, 0);
    acc[1][1] = __builtin_amdgcn_mfma_f32_16x16x32_bf16(a1, b1, acc[1][1], 0, 0, 0);
    acc[1][2] = __builtin_amdgcn_mfma_f32_16x16x32_bf16(a1, b2, acc[1][2], 0, 0, 0);
    acc[1][3] = __builtin_amdgcn_mfma_f32_16x16x32_bf16(a1, b3, acc[1][3], 0, 0, 0);
    acc[2][0] = __builtin_amdgcn_mfma_f32_16x16x32_bf16(a2, b0, acc[2][0], 0, 0, 0);
    acc[2][1] = __builtin_amdgcn_mfma_f32_16x16x32_bf16(a2, b1, acc[2][1], 0, 0, 0);
    acc[2][2] = __builtin_amdgcn_mfma_f32_16x16x32_bf16(a2, b2, acc[2][2], 0, 0, 0);
    acc[2][3] = __builtin_amdgcn_mfma_f32_16x16x32_bf16(a2, b3, acc[2][3], 0, 0, 0);
    acc[3][0] = __builtin_amdgcn_mfma_f32_16x16x32_bf16(a3, b0, acc[3][0], 0, 0, 0);
    acc[3][1] = __builtin_amdgcn_mfma_f32_16x16x32_bf16(a3, b1, acc[3][1], 0, 0, 0);
    acc[3][2] = __builtin_amdgcn_mfma_f32_16x16x32_bf16(a3, b2, acc[3][2], 0, 0, 0);
    acc[3][3] = __builtin_amdgcn_mfma_f32_16x16x32_bf16(a3, b3, acc[3][3], 0, 0, 0);
    __builtin_amdgcn_s_setprio(0);

    // ---- cl1: kk0, mi4-7 x ni0-3 ----
    a0 = *(const short8*)(A0 + abase + 2048);
    a1 = *(const short8*)(A0 + abase + 2560);
    a2 = *(const short8*)(A0 + abase + 3072);
    a3 = *(const short8*)(A0 + abase + 3584);
    if (pf1) { SB_(s1, t + 1, 1, 0); SB_(s1, t + 1, 1, 1); }
    __builtin_amdgcn_s_setprio(1);
    acc[4][0] = __builtin_amdgcn_mfma_f32_16x16x32_bf16(a0, b0, acc[4][0], 0, 0, 0);
    acc[4][1] = __builtin_amdgcn_mfma_f32_16x16x32_bf16(a0, b1, acc[4][1], 0, 0, 0);
    acc[4][2] = __builtin_amdgcn_mfma_f32_16x16x32_bf16(a0, b2, acc[4][2], 0, 0, 0);
    acc[4][3] = __builtin_amdgcn_mfma_f32_16x16x32_bf16(a0, b3, acc[4][3], 0, 0, 0);
    acc[5][0] = __builtin_amdgcn_mfma_f32_16x16x32_bf16(a1, b0, acc[5][0], 0, 0, 0);
    acc[5][1] = __builtin_amdgcn_mfma_f32_16x16x32_bf16(a1, b1, acc[5][1], 0, 0, 0);
    acc[5][2] = __builtin_amdgcn_mfma_f32_16x16x32_bf16(a1, b2, acc[5][2], 0, 0, 0);
    acc[5][3] = __builtin_amdgcn_mfma_f32_16x16x32_bf16(a1, b3, acc[5][3], 0, 0, 0);
    acc[6][0] = __builtin_amdgcn_mfma_f32_16x16x32_bf16(a2, b0, acc[6][0], 0, 0, 0);
    acc[6][1] = __builtin_amdgcn_mfma_f32_16x16x32_bf16(a2, b1, acc[6][1], 0, 0, 0);
    acc[6][2] = __builtin_amdgcn_mfma_f32_16x16x32_bf16(a2, b2, acc[6][2], 0, 0, 0);
    acc[6][3] = __builtin_amdgcn_mfma_f32_16x16x32_bf16(a2, b3, acc[6][3], 0, 0, 0);
    acc[7][0] = __builtin_amdgcn_mfma_f32_16x16x32_bf16(a3, b0, acc[7][0], 0, 0, 0);
    acc[7][1] = __builtin_amdgcn_mfma_f32_16x16x32_bf16(a3, b1, acc[7][1], 0, 0, 0);
    acc[7][2] = __builtin_amdgcn_mfma_f32_16x16x32_bf16(a3, b2, acc[7][2], 0, 0, 0);
    acc[7][3] = __builtin_amdgcn_mfma_f32_16x16x32_bf16(a3, b3, acc[7][3], 0, 0, 0);
    __builtin_amdgcn_s_setprio(0);
    if (t < T - 2) { asm volatile("s_waitcnt vmcnt(8)" ::: "memory"); }
    else           { asm volatile("s_waitcnt vmcnt(0)" ::: "memory"); }
    __builtin_amdgcn_s_barrier();

    // ---- cl2: kk1, mi0-3 x ni0-3 ----
    b0 = *(const short8*)(B1 + bbase);
    b1 = *(const short8*)(B1 + bbase + 512);
    b2 = *(const short8*)(B1 + bbase + 1024);
    b3 = *(const short8*)(B1 + bbase + 1536);
    a0 = *(const short8*)(A1 + abase);
    a1 = *(const short8*)(A1 + abase + 512);
    a2 = *(const short8*)(A1 + abase + 1024);
    a3 = *(const short8*)(A1 + abase + 1536);
    if (pf0) { SA_(s0, t + 2, 0, 0); SA_(s0, t + 2, 0, 1); }
    __builtin_amdgcn_s_setprio(1);
    acc[0][0] = __builtin_amdgcn_mfma_f32_16x16x32_bf16(a0, b0, acc[0][0], 0, 0, 0);
    acc[0][1] = __builtin_amdgcn_mfma_f32_16x16x32_bf16(a0, b1, acc[0][1], 0, 0, 0);
    acc[0][2] = __builtin_amdgcn_mfma_f32_16x16x32_bf16(a0, b2, acc[0][2], 0, 0, 0);
    acc[0][3] = __builtin_amdgcn_mfma_f32_16x16x32_bf16(a0, b3, acc[0][3], 0, 0, 0);
    acc[1][0] = __builtin_amdgcn_mfma_f32_16x16x32_bf16(a1, b0, acc[1][0], 0, 0, 0);
    acc[1][1] = __builtin_amdgcn_mfma_f32_16x16x32_bf16(a1, b1, acc[1][1], 0, 0, 0);
    acc[1][2] = __builtin_amdgcn_mfma_f32_16x16x32_bf16(a1, b2, acc[1][2], 0, 0, 0);
    acc[1][3] = __builtin_amdgcn_mfma_f32_16x16x32_bf16(a1, b3, acc[1][3], 0, 0, 0);
    acc[2][0] = __builtin_amdgcn_mfma_f32_16x16x32_bf16(a2, b0, acc[2][0], 0, 0, 0);
    acc[2][1] = __builtin_amdgcn_mfma_f32_16x16x32_bf16(a2, b1, acc[2][1], 0, 0, 0);
    acc[2][2] = __builtin_amdgcn_mfma_f32_16x16x32_bf16(a2, b2, acc[2][2], 0, 0, 0);
    acc[2][3] = __builtin_amdgcn_mfma_f32_16x16x32_bf16(a2, b3, acc[2][3], 0, 0, 0);
    acc[3][0] = __builtin_amdgcn_mfma_f32_16x16x32_bf16(a3, b0, acc[3][0], 0, 0, 0);
    acc[3][1] = __builtin_amdgcn_mfma_f32_16x16x32_bf16(a3, b1, acc[3][1], 0, 0, 0);
    acc[3][2] = __builtin_amdgcn_mfma_f32_16x16x32_bf16(a3, b2, acc[3][2], 0, 0, 0);
    acc[3][3] = __builtin_amdgcn_mfma_f32_16x16x32_bf16(a3, b3, acc[3][3], 0, 0, 0);
    __builtin_amdgcn_s_setprio(0);

    // ---- cl3: kk1, mi4-7 x ni0-3 ----
    a0 = *(const short8*)(A1 + abase + 2048);
    a1 = *(const short8*)(A1 + abase + 2560);
    a2 = *(const short8*)(A1 + abase + 3072);
    a3 = *(const short8*)(A1 + abase + 3584);
    if (pf0) { SB_(s0, t + 2, 0, 0); SB_(s0, t + 2, 0, 1); }
    __builtin_amdgcn_s_setprio(1);
    acc[4][0] = __builtin_amdgcn_mfma_f32_16x16x32_bf16(a0, b0, acc[4][0], 0, 0, 0);
    acc[4][1] = __builtin_amdgcn_mfma_f32_16x16x32_bf16(a0, b1, acc[4][1], 0, 0, 0);
    acc[4][2] = __builtin_amdgcn_mfma_f32_16x16x32_bf16(a0, b2, acc[4][2], 0, 0, 0);
    acc[4][3] = __builtin_amdgcn_mfma_f32_16x16x32_bf16(a0, b3, acc[4][3], 0, 0, 0);
    acc[5][0] = __builtin_amdgcn_mfma_f32_16x16x32_bf16(a1, b0, acc[5][0], 0, 0, 0);
    acc[5][1] = __builtin_amdgcn_mfma_f32_16x16x32_bf16(a1, b1, acc[5][1], 0, 0, 0);
    acc[5][2] = __builtin_amdgcn_mfma_f32_16x16x32_bf16(a1, b2, acc[5][2], 0, 0, 0);
    acc[5][3] = __builtin_amdgcn_mfma_f32_16x16x32_bf16(a1, b3, acc[5][3], 0, 0, 0);
    acc[6][0] = __builtin_amdgcn_mfma_f32_16x16x32_bf16(a2, b0, acc[6][0], 0, 0, 0);
    acc[6][1] = __builtin_amdgcn_mfma_f32_16x16x32_bf16(a2, b1, acc[6][1], 0, 0, 0);
    acc[6][2] = __builtin_amdgcn_mfma_f32_16x16x32_bf16(a2, b2, acc[6][2], 0, 0, 0);
    acc[6][3] = __builtin_amdgcn_mfma_f32_16x16x32_bf16(a2, b3, acc[6][3], 0, 0, 0);
    acc[7][0] = __builtin_amdgcn_mfma_f32_16x16x32_bf16(a3, b0, acc[7][0], 0, 0, 0);
    acc[7][1] = __builtin_amdgcn_mfma_f32_16x16x32_bf16(a3, b1, acc[7][1], 0, 0, 0);
    acc[7][2] = __builtin_amdgcn_mfma_f32_16x16x32_bf16(a3, b2, acc[7][2], 0, 0, 0);
    acc[7][3] = __builtin_amdgcn_mfma_f32_16x16x32_bf16(a3, b3, acc[7][3], 0, 0, 0);
    __builtin_amdgcn_s_setprio(0);
    if (t < T - 2) { asm volatile("s_waitcnt vmcnt(8)" ::: "memory"); }
    else           { asm volatile("s_waitcnt vmcnt(0)" ::: "memory"); }
    __builtin_amdgcn_s_barrier();
  }
#undef SA_
#undef SB_

  // ---- epilogue ----
  ushort_t* Pz = (OUT == 2)
      ? (ushort_t*)Cout + (size_t)blockIdx.z * M * N : (ushort_t*)Cout;
#pragma unroll
  for (int mi = 0; mi < 8; ++mi) {
#pragma unroll
    for (int ni = 0; ni < 4; ++ni) {
      const int gn = n0 + wc * 64 + ni * 16 + lr;
      const float bvv = (OUT == 2) ? 0.f : bias[gn];
#pragma unroll
      for (int j = 0; j < 4; ++j) {
        const int gm = m0 + wr * 128 + mi * 16 + lg * 4 + j;
        float v = acc[mi][ni][j] + bvv;
        if (RESID) v += resid[(size_t)gm * N + gn];
        if (RELU) v = fmaxf(v, 0.f);
        if (OUT == 0)      ((float*)Cout)[(size_t)gm * N + gn] = v;
        else               Pz[(size_t)gm * N + gn] = f2bf(v);
      }
    }
  }
}

// ---------------- split-K combine: out = p0 + p1 + bias + resid (fp32) -----
__global__ __launch_bounds__(256) void combine_kern(
    const ushort_t* __restrict__ pp, const float* __restrict__ bias,
    const float* __restrict__ resid, float* __restrict__ out)
{
  const size_t i = ((size_t)blockIdx.x * 256 + threadIdx.x) * 8;
  ushort8 p0 = *(const ushort8*)(pp + i);
  ushort8 p1 = *(const ushort8*)(pp + (size_t)MROWS * 2048 + i);
  const int col = (int)(i & 2047);
  float4 r0 = *(const float4*)(resid + i);
  float4 r1 = *(const float4*)(resid + i + 4);
  float4 c0 = *(const float4*)(bias + col);
  float4 c1 = *(const float4*)(bias + col + 4);
  float4 o0, o1;
  o0.x = bf2f(p0[0]) + bf2f(p1[0]) + c0.x + r0.x;
  o0.y = bf2f(p0[1]) + bf2f(p1[1]) + c0.y + r0.y;
  o0.z = bf2f(p0[2]) + bf2f(p1[2]) + c0.z + r0.z;
  o0.w = bf2f(p0[3]) + bf2f(p1[3]) + c0.w + r0.w;
  o1.x = bf2f(p0[4]) + bf2f(p1[4]) + c1.x + r1.x;
  o1.y = bf2f(p0[5]) + bf2f(p1[5]) + c1.y + r1.y;
  o1.z = bf2f(p0[6]) + bf2f(p1[6]) + c1.z + r1.z;
  o1.w = bf2f(p0[7]) + bf2f(p1[7]) + c1.w + r1.w;
  *(float4*)(out + i) = o0;
  *(float4*)(out + i + 4) = o1;
}

// ---------------- attention stats -----------------------------------------
__global__ __launch_bounds__(256) void attn_stats_kern(
    const ushort_t* __restrict__ Q, const ushort_t* __restrict__ Kb,
    float* __restrict__ E, float* __restrict__ DG, int ld)
{
  __shared__ ushort_t Ksm[64 * 128];   // 16 KB
  const int qb = blockIdx.x;           // 0..31 -> q rows [qb*64, qb*64+64)
  const int bh = blockIdx.y;           // 0..31
  const int b = bh >> 4, h = bh & 15;
  const int tid = threadIdx.x;
  const int l = tid & 63, w = tid >> 6;
  const int lr = l & 15, lg = l >> 4;

  const int qrow0 = qb * 64 + w * 16;  // wave's q-subtile

  const size_t qoff = (size_t)(b * SEQ + qrow0 + lr) * ld + h * DHEAD + lg * 8;
  short8 af[4];
#pragma unroll
  for (int c = 0; c < 4; ++c) af[c] = *(const short8*)(Q + qoff + c * 32);

  const int srow_b = w * 16 + (l >> 4);           // + c*4
  const ushort_t* Kg = Kb + (size_t)b * SEQ * ld + (size_t)h * DHEAD;
  ushort_t* Sbase = Ksm + w * 2048;               // + c*512 (ushort units)

  f32x4 sume = {0.f, 0.f, 0.f, 0.f};
  f32x4 dge  = {0.f, 0.f, 0.f, 0.f};
  const float scale = 0.0220970869120796f;        // 1/sqrt(2048)
  const int rx = lr & 7;                          // read-side xor key

  for (int kc = qb; kc < 32; ++kc) {
    __syncthreads();
#pragma unroll
    for (int c = 0; c < 4; ++c) {
      const int row = srow_b + c * 4;
      const int g = (l & 15) ^ (row & 7);
      __builtin_amdgcn_global_load_lds(
          GPTR(Kg + (size_t)(kc * 64 + row) * ld + g * 8),
          SPTR(Sbase + c * 512), 16, 0, 0);
    }
    __syncthreads();

    const int ks0 = (kc == qb) ? w : 0;           // skip fully-masked subtiles
    for (int ks = ks0; ks < 4; ++ks) {
      short8 bfr[4];
#pragma unroll
      for (int c = 0; c < 4; ++c)
        bfr[c] = *(const short8*)(Ksm + (ks * 16 + lr) * 128 + ((lg + c * 4) ^ rx) * 8);
      f32x4 sc = {0.f, 0.f, 0.f, 0.f};
      sc = __builtin_amdgcn_mfma_f32_16x16x32_bf16(af[0], bfr[0], sc, 0, 0, 0);
      sc = __builtin_amdgcn_mfma_f32_16x16x32_bf16(af[1], bfr[1], sc, 0, 0, 0);
      sc = __builtin_amdgcn_mfma_f32_16x16x32_bf16(af[2], bfr[2], sc, 0, 0, 0);
      sc = __builtin_amdgcn_mfma_f32_16x16x32_bf16(af[3], bfr[3], sc, 0, 0, 0);
      if (kc == qb && ks == w) {
        const int ki = kc * 64 + ks * 16 + lr;
#pragma unroll
        for (int j = 0; j < 4; ++j) {
          const int qi = qrow0 + lg * 4 + j;
          if (ki >= qi) {
            float e = __expf(sc[j] * scale);
            sume[j] += e;
            if (ki == qi) dge[j] += e;
          }
        }
      } else {
#pragma unroll
        for (int j = 0; j < 4; ++j)
          sume[j] += __expf(sc[j] * scale);
      }
    }
  }

#pragma unroll
  for (int j = 0; j < 4; ++j) {
#pragma unroll
    for (int off = 1; off < 16; off <<= 1) {
      sume[j] += __shfl_xor(sume[j], off);
      dge[j]  += __shfl_xor(dge[j], off);
    }
  }
  if (lr == 0) {
#pragma unroll
    for (int j = 0; j < 4; ++j) {
      E[(size_t)bh * SEQ + qrow0 + lg * 4 + j]  = sume[j];
      DG[(size_t)bh * SEQ + qrow0 + lg * 4 + j] = dge[j];
    }
  }
}

// ---------------- V chunk sums (64-row chunks) -----------------------------
__global__ __launch_bounds__(128) void vchunk_kern(
    const ushort_t* __restrict__ V, float* __restrict__ CS, int ld)
{
  const int c = blockIdx.x, bh = blockIdx.y;
  const int b = bh >> 4, h = bh & 15;
  const int dh = threadIdx.x;
  const ushort_t* vp = V + (size_t)(b * SEQ + c * 64) * ld + h * DHEAD + dh;
  float s = 0.f;
  for (int i = 0; i < 64; ++i) s += bf2f(vp[(size_t)i * ld]);
  CS[((size_t)bh * 32 + c) * 128 + dh] = s;
}

// ---------------- combine: attn = (prefixV + diag*v)/denom -> bf16 ---------
__global__ __launch_bounds__(128) void attn_combine_kern(
    const ushort_t* __restrict__ V, const float* __restrict__ CS,
    const float* __restrict__ E, const float* __restrict__ DG,
    ushort_t* __restrict__ Attn, int ldv)
{
  const int c = blockIdx.x, bh = blockIdx.y;
  const int b = bh >> 4, h = bh & 15;
  const int dh = threadIdx.x;
  float prefix = 0.f;
  for (int cc = 0; cc < c; ++cc) prefix += CS[((size_t)bh * 32 + cc) * 128 + dh];
  const ushort_t* vp = V + (size_t)(b * SEQ + c * 64) * ldv + h * DHEAD + dh;
  ushort_t* ap = Attn + (size_t)(b * SEQ + c * 64) * DMODEL + h * DHEAD + dh;
  const int qb = c * 64;
  for (int i = 0; i < 64; ++i) {
    const int qq = qb + i;
    const float denom = (float)qq + E[(size_t)bh * SEQ + qq];
    const float de = DG[(size_t)bh * SEQ + qq];
    const float vv = bf2f(vp[(size_t)i * ldv]);
    ap[(size_t)i * DMODEL] = f2bf((prefix + de * vv) / denom);
    prefix += vv;
  }
}

// ---------------------------------------------------------------------------
extern "C" void kernel_launch(void* const* d_in, const int* in_sizes, int n_in,
                              void* d_out, int out_size, void* d_ws, size_t ws_size,
                              hipStream_t stream)
{
  const float* x    = (const float*)d_in[0];
  const float* wq   = (const float*)d_in[1];
  const float* bq   = (const float*)d_in[2];
  const float* wk   = (const float*)d_in[3];
  const float* bk   = (const float*)d_in[4];
  const float* wv   = (const float*)d_in[5];
  const float* bv   = (const float*)d_in[6];
  const float* wo   = (const float*)d_in[7];
  const float* bo   = (const float*)d_in[8];
  const float* ln1g = (const float*)d_in[9];
  const float* ln1b = (const float*)d_in[10];
  const float* w1   = (const float*)d_in[11];
  const float* b1   = (const float*)d_in[12];
  const float* w2   = (const float*)d_in[13];
  const float* b2   = (const float*)d_in[14];
  const float* ln2g = (const float*)d_in[15];
  const float* ln2b = (const float*)d_in[16];
  float* out = (float*)d_out;

  // ws layout (bytes):
  //   W1T 0..32M (dead after FF1 -> FF2 partials live here)
  //   W2T 32M..64M ; WOT 64M..72M
  //   X2 72M..104M fp32 (Bcat overlaps head, dead before X2 written)
  //   Hb 104M..120M (h / attn / h2)
  //   F1 region 120M..184M: WO partials (2x16M bf16) live here before FF1;
  //     also overlaps WQKV (120M..144M) and QKVb (144M..192M) which are dead
  //     by WO time. F1 (FF1 out) written after WO-combine.
  char* ws = (char*)d_ws;
  ushort_t* W1T  = (ushort_t*)(ws + 0);            // 33554432
  ushort_t* PPf2 = (ushort_t*)(ws + 0);            // FF2 partials (reuse W1T)
  ushort_t* W2T  = (ushort_t*)(ws + 33554432);     // 33554432
  ushort_t* WOT  = (ushort_t*)(ws + 67108864);     //  8388608
  float*    X2   = (float*)   (ws + 75497472);     // 33554432 (fp32)
  float*    Bcat = (float*)   (ws + 75497472);     //    24576 (dead before X2)
  ushort_t* Hb   = (ushort_t*)(ws + 109051904);    // 16777216 (h / attn / h2)
  ushort_t* F1   = (ushort_t*)(ws + 125829120);    // 67108864 (overlaps below)
  ushort_t* PPwo = (ushort_t*)(ws + 125829120);    // WO partials (2x16M)
  ushort_t* WQKV = (ushort_t*)(ws + 125829120);    // 25165824 (6144 x 2048)
  ushort_t* QKVb = (ushort_t*)(ws + 150994944);    // 50331648 (4096 x 6144)
  float*    Eb   = (float*)   (ws + 201326592);    //   262144
  float*    DGb  = (float*)   (ws + 201588736);    //   262144
  float*    CSb  = (float*)   (ws + 201850880);    //   524288

  // 1. weight transposes (fp32 -> bf16 [N][K]); wq/wk/wv stacked into WQKV
  transpose_f32_bf16_kern<<<dim3(64, 64),  256, 0, stream>>>(wq, WQKV,                   2048, 2048);
  transpose_f32_bf16_kern<<<dim3(64, 64),  256, 0, stream>>>(wk, WQKV + 2048 * 2048,     2048, 2048);
  transpose_f32_bf16_kern<<<dim3(64, 64),  256, 0, stream>>>(wv, WQKV + 2 * 2048 * 2048, 2048, 2048);
  transpose_f32_bf16_kern<<<dim3(64, 64),  256, 0, stream>>>(wo, WOT, 2048, 2048);
  transpose_f32_bf16_kern<<<dim3(256, 64), 256, 0, stream>>>(w1, W1T, 2048, 8192);
  transpose_f32_bf16_kern<<<dim3(64, 256), 256, 0, stream>>>(w2, W2T, 8192, 2048);
  bias_concat_kern<<<24, 256, 0, stream>>>(bq, bk, bv, Bcat);

  // 2. LN1: x -> h (bf16)
  ln_kern<<<MROWS, 256, 0, stream>>>(x, ln1g, ln1b, Hb);

  // 3. fused QKV projection -> QKVb [4096][6144]   (grid: x=n, y=m)
  gemm8_kern<1, 0, 0, 1><<<dim3(24, 16), 512, 0, stream>>>(
      Hb, WQKV, Bcat, nullptr, QKVb, MROWS, LDQKV, DMODEL);

  // 4. attention stats (upper-tri exp row sums + diagonal)
  attn_stats_kern<<<dim3(32, 32), 256, 0, stream>>>(QKVb, QKVb + 2048, Eb, DGb, LDQKV);

  // 5. V prefix machinery + combine -> attn (into Hb, h is dead)
  vchunk_kern<<<dim3(32, 32), 128, 0, stream>>>(QKVb + 4096, CSb, LDQKV);
  attn_combine_kern<<<dim3(32, 32), 128, 0, stream>>>(QKVb + 4096, CSb, Eb, DGb, Hb, LDQKV);

  // 6. O projection, split-K=2 -> bf16 partials; combine + bo + x -> X2
  gemm8_kern<2, 0, 0, 2><<<dim3(8, 16, 2), 512, 0, stream>>>(
      Hb, WOT, bo, nullptr, PPwo, MROWS, DMODEL, DMODEL);
  combine_kern<<<4096, 256, 0, stream>>>(PPwo, bo, x, X2);

  // 7. LN2: X2 -> h2 (bf16, reuse Hb)
  ln_kern<<<MROWS, 256, 0, stream>>>(X2, ln2g, ln2b, Hb);

  // 8. FF1 + ReLU -> F1 (bf16)
  gemm8_kern<1, 1, 0, 1><<<dim3(32, 16), 512, 0, stream>>>(
      Hb, W1T, b1, nullptr, F1, MROWS, DFFN, DMODEL);

  // 9. FF2 split-K=2 -> bf16 partials (W1T region); combine + b2 + X2 -> out
  gemm8_kern<2, 0, 0, 2><<<dim3(8, 16, 2), 512, 0, stream>>>(
      F1, W2T, b2, nullptr, PPf2, MROWS, DMODEL, DFFN);
  combine_kern<<<4096, 256, 0, stream>>>(PPf2, b2, X2, out);
}